// Round 19
// baseline (767.370 us; speedup 1.0000x reference)
//
#include <hip/hip_runtime.h>
#include <math.h>

#define EN 256000
#define NN 40000
#define NR 474
#define EPS_ 1e-5f

typedef unsigned short u16;
typedef __attribute__((ext_vector_type(4))) float f4_t;
typedef __attribute__((ext_vector_type(8))) short bf8_t;
typedef __attribute__((ext_vector_type(4))) float facc_t;

__device__ __forceinline__ float sigm(float x) { return 1.f / (1.f + __expf(-x)); }
__device__ __forceinline__ float tanh_f(float x) { float e = __expf(2.f * x); return 1.f - 2.f / (e + 1.f); }

__device__ __forceinline__ u16 f2bf(float f) {
    unsigned u = __float_as_uint(f);
    return (u16)((u + 0x7FFFu + ((u >> 16) & 1u)) >> 16);
}
__device__ __forceinline__ unsigned cvtpk(float lo, float hi) {
    unsigned r;
    asm("v_cvt_pk_bf16_f32 %0, %1, %2" : "=v"(r) : "v"(lo), "v"(hi));
    return r;
}
__device__ __forceinline__ u16 f2bf_hw(float v) { return (u16)cvtpk(v, v); }
__device__ __forceinline__ float bf2f(u16 u) { return __uint_as_float(((unsigned)u) << 16); }

__device__ __forceinline__ bf8_t pack8(f4_t a, f4_t b) {
    union { unsigned u[4]; bf8_t v; } r;
    r.u[0] = cvtpk(a[0], a[1]);
    r.u[1] = cvtpk(a[2], a[3]);
    r.u[2] = cvtpk(b[0], b[1]);
    r.u[3] = cvtpk(b[2], b[3]);
    return r.v;
}
__device__ __forceinline__ void unpk8(bf8_t v, f4_t& a, f4_t& b) {
    a[0] = bf2f((u16)v[0]); a[1] = bf2f((u16)v[1]); a[2] = bf2f((u16)v[2]); a[3] = bf2f((u16)v[3]);
    b[0] = bf2f((u16)v[4]); b[1] = bf2f((u16)v[5]); b[2] = bf2f((u16)v[6]); b[3] = bf2f((u16)v[7]);
}

// swizzled u16 index into a 16x64 wave tile (see round-11 analysis)
__device__ __forceinline__ int tswz(int r, int u) {
    return r * 64 + (u ^ (((r >> 2) & 3) << 4));
}

__device__ __forceinline__ void wave_ln64(float v, float& mean, float& var) {
    float s = v, s2 = v * v;
    #pragma unroll
    for (int off = 32; off > 0; off >>= 1) { s += __shfl_xor(s, off, 64); s2 += __shfl_xor(s2, off, 64); }
    mean = s * (1.f / 64.f);
    var = s2 * (1.f / 64.f) - mean * mean;
}

// ---------------- init / graph prep ----------------

__global__ void k_init(u16* efeat, u16* nfeat, int* cnt, int* outcnt, float* avg_sum) {
    long total = (long)EN * 32;
    unsigned* ef = (unsigned*)efeat;
    unsigned* nf = (unsigned*)nfeat;
    for (long i = blockIdx.x * (long)blockDim.x + threadIdx.x; i < total; i += (long)gridDim.x * blockDim.x) {
        ef[i] = 0u;
        if (i < (long)NN * 32) nf[i] = 0u;
        if (i < NN) { cnt[i] = 0; outcnt[i] = 0; }
        if (i == 0) avg_sum[0] = 0.f;
    }
}

__global__ void k_count(const int* __restrict__ src, const int* __restrict__ dst, int* cnt, int* outcnt) {
    for (int e = blockIdx.x * blockDim.x + threadIdx.x; e < EN; e += gridDim.x * blockDim.x) {
        atomicAdd(&cnt[dst[e]], 1);
        atomicAdd(&outcnt[src[e]], 1);
    }
}

// 3-kernel device-wide exclusive scan
__global__ void k_scan1(const int* __restrict__ cnt, int* __restrict__ row_ptr, int* __restrict__ bsum) {
    __shared__ int tmp[1024];
    const int b = blockIdx.x, t = threadIdx.x;
    const int idx = b * 1024 + t;
    const int v = (idx < NN) ? cnt[idx] : 0;
    tmp[t] = v;
    __syncthreads();
    for (int off = 1; off < 1024; off <<= 1) {
        int u = (t >= off) ? tmp[t - off] : 0;
        __syncthreads();
        tmp[t] += u;
        __syncthreads();
    }
    if (idx < NN) row_ptr[idx] = tmp[t] - v;
    if (t == 1023) bsum[b] = tmp[t];
}

__global__ void k_scan2(const int* __restrict__ bsum, int* __restrict__ boff, int* __restrict__ row_ptr) {
    const int t = threadIdx.x;
    const int v = (t < 40) ? bsum[t] : 0;
    int s = v;
    #pragma unroll
    for (int off = 1; off < 64; off <<= 1) {
        int u = __shfl_up(s, off, 64);
        if (t >= off) s += u;
    }
    if (t < 40) boff[t] = s - v;
    if (t == 63) row_ptr[NN] = s;
}

__global__ void k_scan3(int* __restrict__ row_ptr, int* __restrict__ fillp, const int* __restrict__ boff) {
    const int idx = blockIdx.x * 1024 + threadIdx.x;
    if (idx < NN) {
        const int r = row_ptr[idx] + boff[blockIdx.x];
        row_ptr[idx] = r;
        fillp[idx] = r;
    }
}

__global__ void k_fill(const int* __restrict__ dst, int* fillp, int* eid) {
    for (int e = blockIdx.x * blockDim.x + threadIdx.x; e < EN; e += gridDim.x * blockDim.x) {
        int pos = atomicAdd(&fillp[dst[e]], 1);
        eid[pos] = e;
    }
}

__global__ void k_avg(const int* __restrict__ outcnt, float* __restrict__ avg_sum) {
    int n = blockIdx.x * blockDim.x + threadIdx.x;
    float v = 0.f;
    if (n < NN) v = logf((float)outcnt[n] + 1.f);
    #pragma unroll
    for (int off = 32; off > 0; off >>= 1) v += __shfl_xor(v, off, 64);
    if ((threadIdx.x & 63) == 0) atomicAdd(avg_sum, v);
}

__global__ void k_tgt(const int* __restrict__ tgt, const int* __restrict__ etype,
                      const float* __restrict__ query_emb, float* tgt_q, u16* efeat) {
    int t = blockIdx.x, d = threadIdx.x;
    int e = tgt[t];
    int r = etype[e];
    float v = query_emb[r * 64 + d];
    tgt_q[t * 64 + d] = v;
    efeat[(size_t)e * 64 + d] = f2bf(v);
}

__global__ void k_eqg(const float* __restrict__ tgt_q, const float* __restrict__ eqp_w,
                      const float* __restrict__ eqp_b, float* eq_g) {
    int g = blockIdx.x, d = threadIdx.x;
    float acc = eqp_b[d];
    for (int k = 0; k < 128; k++) {
        float a = tgt_q[(2 * g + (k >> 6)) * 64 + (k & 63)];
        acc += a * eqp_w[k * 64 + d];
    }
    eq_g[g * 64 + d] = acc;
}

__global__ void k_equery(const int* __restrict__ egid, const float* __restrict__ eq_g, u16* equery) {
    long total = (long)EN * 64;
    for (long i = blockIdx.x * (long)blockDim.x + threadIdx.x; i < total; i += (long)gridDim.x * blockDim.x) {
        int e = (int)(i >> 6), d = (int)(i & 63);
        equery[i] = f2bf(eq_g[egid[e] * 64 + d]);
    }
}

// ---------------- layer-0 GRU specialization ----------------

__global__ void k_gru0_rows(const float* __restrict__ eq_g, const float* __restrict__ wx,
                            const float* __restrict__ bx, const float* __restrict__ bh,
                            u16* __restrict__ msg_row) {
    const int g = blockIdx.x, d = threadIdx.x;  // 32 x 64
    float ar = bx[d], az = bx[64 + d], an = bx[128 + d];
    for (int k = 0; k < 64; k++) {
        const float x = bf2f(f2bf(eq_g[g * 64 + k]));
        ar += x * wx[k * 192 + d];
        az += x * wx[k * 192 + 64 + d];
        an += x * wx[k * 192 + 128 + d];
    }
    const float r = sigm(ar + bh[d]);
    const float z = sigm(az + bh[64 + d]);
    const float n = tanh_f(an + r * bh[128 + d]);
    msg_row[g * 64 + d] = f2bf((1.f - z) * n);
}

__global__ void k_gru0_scatter(const int* __restrict__ egid, const u16* __restrict__ msg_row,
                               u16* __restrict__ msg) {
    long total = (long)EN * 32;
    const unsigned* mr = (const unsigned*)msg_row;
    unsigned* m = (unsigned*)msg;
    for (long i = blockIdx.x * (long)blockDim.x + threadIdx.x; i < total; i += (long)gridDim.x * blockDim.x) {
        const int e = (int)(i >> 5);
        const int dd = (int)(i & 31);
        m[i] = mr[egid[e] * 32 + dd];
    }
}

__global__ void k_gru0_fix(const int* __restrict__ tgt, const int* __restrict__ etype,
                           const u16* __restrict__ equery, const u16* __restrict__ efeat,
                           const float* __restrict__ relw,
                           const float* __restrict__ wx, const float* __restrict__ wh,
                           const float* __restrict__ bx, const float* __restrict__ bh,
                           u16* __restrict__ msg) {
    const int t = blockIdx.x, d = threadIdx.x;  // 64 x 64
    const int e = tgt[t];
    const int ty = etype[e];
    float ar = bx[d], az = bx[64 + d], an = bx[128 + d];
    float br = bh[d], bz = bh[64 + d], bn = bh[128 + d];
    for (int k = 0; k < 64; k++) {
        const float x = bf2f(equery[(size_t)e * 64 + k]);
        const float h = bf2f(efeat[(size_t)e * 64 + k]) * relw[ty * 64 + k];
        ar += x * wx[k * 192 + d];       br += h * wh[k * 192 + d];
        az += x * wx[k * 192 + 64 + d];  bz += h * wh[k * 192 + 64 + d];
        an += x * wx[k * 192 + 128 + d]; bn += h * wh[k * 192 + 128 + d];
    }
    const float r = sigm(ar + br);
    const float z = sigm(az + bz);
    const float n = tanh_f(an + r * bn);
    const float h_ = bf2f(efeat[(size_t)e * 64 + d]) * relw[ty * 64 + d];
    msg[(size_t)e * 64 + d] = f2bf_hw((1.f - z) * n + z * h_);
}

// ---------------- layer-0 LSTM specialization ----------------
// At l=0 entry: efeat==0 except 64 target edges -> gates depend only on dst
// node (40k rows vs 256k edges; Wx half only). equery is the 32-row broadcast.
// gates: per-node MFMA GEMM -> bf16 gates buffer (20MB, L2-resident).
// apply: per-edge elementwise (coalesced gate reads, eq from LDS, wave-LN).
// fix: exact fp32 recompute of the 64 target edges (efeat@Wh != 0 there).

__launch_bounds__(256, 1)
__global__ void k_lstm0_gates(const u16* __restrict__ nfeat_new, const u16* __restrict__ wpack,
                              const float* __restrict__ bb, u16* __restrict__ gates) {
    __shared__ u16 sW[16384];     // Wx half of the pack (ks=0,1 -> recs 0..31)
    __shared__ u16 sT[4][4096];   // 16 nodes x 256 u16 per wave
    const int tid = threadIdx.x;
    const int lane = tid & 63;
    const int wv = tid >> 6;
    {
        const uint4* gsrc = (const uint4*)wpack;
        uint4* ldst = (uint4*)sW;
        #pragma unroll
        for (int i = 0; i < 8; i++) ldst[tid + i * 256] = gsrc[tid + i * 256];
    }
    __syncthreads();

    const int row = lane & 15, kg = lane >> 4;
    u16* tile = sT[wv];
    const int NC = NN / 16;
    const int stride = gridDim.x * 4;
    for (int ch = blockIdx.x * 4 + wv; ch < NC; ch += stride) {
        const int base = ch * 16;
        const int v = base + row;
        bf8_t af0 = *(const bf8_t*)(nfeat_new + (size_t)v * 64 + kg * 8);
        bf8_t af1 = *(const bf8_t*)(nfeat_new + (size_t)v * 64 + 32 + kg * 8);
        #pragma unroll
        for (int w = 0; w < 4; w++) {
            facc_t ai = {0.f, 0.f, 0.f, 0.f}, af_ = ai, ag = ai, ao = ai;
            #pragma unroll
            for (int ks = 0; ks < 2; ks++) {
                const int rb = (ks * 16 + w * 4) * 512 + lane * 8;
                bf8_t b0 = *(const bf8_t*)&sW[rb];
                bf8_t b1 = *(const bf8_t*)&sW[rb + 512];
                bf8_t b2 = *(const bf8_t*)&sW[rb + 1024];
                bf8_t b3 = *(const bf8_t*)&sW[rb + 1536];
                const bf8_t a = ks == 0 ? af0 : af1;
                ai  = __builtin_amdgcn_mfma_f32_16x16x32_bf16(a, b0, ai, 0, 0, 0);
                af_ = __builtin_amdgcn_mfma_f32_16x16x32_bf16(a, b1, af_, 0, 0, 0);
                ag  = __builtin_amdgcn_mfma_f32_16x16x32_bf16(a, b2, ag, 0, 0, 0);
                ao  = __builtin_amdgcn_mfma_f32_16x16x32_bf16(a, b3, ao, 0, 0, 0);
            }
            const int d = w * 16 + row;
            const float bi = bb[d], bf_ = bb[64 + d], bg = bb[128 + d], bo = bb[192 + d];
            #pragma unroll
            for (int rr = 0; rr < 4; rr++) {
                const int m = kg * 4 + rr;
                const int sx = (((m >> 2) & 3) << 4);
                tile[m * 256 + ((d) ^ sx)]        = f2bf_hw(ai[rr] + bi);
                tile[m * 256 + ((64 + d) ^ sx)]   = f2bf_hw(af_[rr] + bf_);
                tile[m * 256 + ((128 + d) ^ sx)]  = f2bf_hw(ag[rr] + bg);
                tile[m * 256 + ((192 + d) ^ sx)]  = f2bf_hw(ao[rr] + bo);
            }
        }
        // bulk store 8KB as contiguous bursts (unswizzle on read)
        #pragma unroll
        for (int i = 0; i < 8; i++) {
            const int j = i * 512 + lane * 8;
            const int mp = j >> 8, off = j & 255;
            bf8_t v8 = *(const bf8_t*)&tile[mp * 256 + (off ^ (((mp >> 2) & 3) << 4))];
            *(bf8_t*)(gates + (size_t)base * 256 + j) = v8;
        }
    }
}

__global__ void k_lstm0_apply(const int* __restrict__ dst, const u16* __restrict__ gates,
                              const float* __restrict__ eq_g,
                              const float* __restrict__ g_ln, const float* __restrict__ b_ln,
                              u16* __restrict__ efeat, u16* __restrict__ equery) {
    __shared__ float sEq[2048];
    const int tid = threadIdx.x;
    const int lane = tid & 63;
    const int wv = tid >> 6;
    for (int i = tid; i < 2048; i += 256) sEq[i] = bf2f(f2bf(eq_g[i]));
    __syncthreads();
    const float lg = g_ln[lane], lb = b_ln[lane];
    const int nw = gridDim.x * 4;
    for (int e = blockIdx.x * 4 + wv; e < EN; e += nw) {
        const int gid = e / 8000;
        if (e - gid * 8000 < 2) continue;  // 64 target edges handled by fix
        const int de = dst[e];
        const size_t gb = (size_t)de * 256;
        const float gi = bf2f(gates[gb + lane]);
        const float gf = bf2f(gates[gb + 64 + lane]);
        const float gg = bf2f(gates[gb + 128 + lane]);
        const float go = bf2f(gates[gb + 192 + lane]);
        const float eq = sEq[gid * 64 + lane];
        const float c_ = sigm(gf) * eq + sigm(gi) * tanh_f(gg);
        const float h_ = sigm(go) * tanh_f(c_);
        float hm, hv, cm, cv;
        wave_ln64(h_, hm, hv);
        wave_ln64(c_, cm, cv);
        efeat[(size_t)e * 64 + lane] = f2bf_hw((h_ - hm) * rsqrtf(hv + EPS_) * lg + lb);
        equery[(size_t)e * 64 + lane] = f2bf_hw(eq + (c_ - cm) * rsqrtf(cv + EPS_) * lg + lb);
    }
}

__global__ void k_lstm0_fix(const int* __restrict__ tgt, const int* __restrict__ dst,
                            const u16* __restrict__ nfeat_new,
                            const float* __restrict__ wx, const float* __restrict__ wh,
                            const float* __restrict__ bb,
                            const float* __restrict__ g_ln, const float* __restrict__ b_ln,
                            u16* __restrict__ efeat, u16* __restrict__ equery) {
    const int t = blockIdx.x, d = threadIdx.x;  // 64 x 64 (one wave/block)
    const int e = tgt[t];
    const int de = dst[e];
    float ai = bb[d], af_ = bb[64 + d], ag = bb[128 + d], ao = bb[192 + d];
    for (int k = 0; k < 64; k++) {
        const float x = bf2f(nfeat_new[(size_t)de * 64 + k]);
        const float ef = bf2f(efeat[(size_t)e * 64 + k]);   // original (apply skipped)
        ai  += x * wx[k * 256 + d]       + ef * wh[k * 256 + d];
        af_ += x * wx[k * 256 + 64 + d]  + ef * wh[k * 256 + 64 + d];
        ag  += x * wx[k * 256 + 128 + d] + ef * wh[k * 256 + 128 + d];
        ao  += x * wx[k * 256 + 192 + d] + ef * wh[k * 256 + 192 + d];
    }
    const float eq = bf2f(equery[(size_t)e * 64 + d]);
    const float efo = bf2f(efeat[(size_t)e * 64 + d]);
    const float c_ = sigm(af_) * eq + sigm(ai) * tanh_f(ag);
    const float h_ = sigm(ao) * tanh_f(c_);
    float hm, hv, cm, cv;
    wave_ln64(h_, hm, hv);
    wave_ln64(c_, cm, cv);
    __syncthreads();  // all efeat/equery row reads complete before writes
    efeat[(size_t)e * 64 + d] = f2bf_hw(efo + (h_ - hm) * rsqrtf(hv + EPS_) * g_ln[d] + b_ln[d]);
    equery[(size_t)e * 64 + d] = f2bf_hw(eq + (c_ - cm) * rsqrtf(cv + EPS_) * g_ln[d] + b_ln[d]);
}

// ---------------- weight packing for MFMA ----------------

__global__ void k_pack_gru(const float* __restrict__ wx, const float* __restrict__ wh,
                           u16* __restrict__ out) {
    int l = blockIdx.y;
    wx += (size_t)l * 64 * 192; wh += (size_t)l * 64 * 192; out += (size_t)l * 32768;
    for (int idx = blockIdx.x * blockDim.x + threadIdx.x; idx < 32768; idx += gridDim.x * blockDim.x) {
        int rec = idx >> 3, j = idx & 7;
        int lane = rec & 63, ksnt = rec >> 6;
        int nt = ksnt & 15, ks = ksnt >> 4;
        int k = ks * 32 + (lane >> 4) * 8 + j;
        int g = nt & 3, d = (nt >> 2) * 16 + (lane & 15);
        float v;
        if (g == 0)      v = k < 64 ? wx[k * 192 + d]        : wh[(k - 64) * 192 + d];
        else if (g == 1) v = k < 64 ? wx[k * 192 + 64 + d]   : wh[(k - 64) * 192 + 64 + d];
        else if (g == 2) v = k < 64 ? wx[k * 192 + 128 + d]  : 0.f;
        else             v = k < 64 ? 0.f                    : wh[(k - 64) * 192 + 128 + d];
        out[idx] = f2bf(v);
    }
}

__global__ void k_pack_lstm(const float* __restrict__ wx, const float* __restrict__ wh,
                            u16* __restrict__ out) {
    int l = blockIdx.y;
    wx += (size_t)l * 64 * 256; wh += (size_t)l * 64 * 256; out += (size_t)l * 32768;
    for (int idx = blockIdx.x * blockDim.x + threadIdx.x; idx < 32768; idx += gridDim.x * blockDim.x) {
        int rec = idx >> 3, j = idx & 7;
        int lane = rec & 63, ksnt = rec >> 6;
        int nt = ksnt & 15, ks = ksnt >> 4;
        int k = ks * 32 + (lane >> 4) * 8 + j;
        int g = nt & 3, d = (nt >> 2) * 16 + (lane & 15);
        float v = k < 64 ? wx[k * 256 + g * 64 + d] : wh[(k - 64) * 256 + g * 64 + d];
        out[idx] = f2bf(v);
    }
}

__global__ void k_pack_pna(const float* __restrict__ pw, u16* __restrict__ out) {
    int l = blockIdx.y;
    pw += (size_t)l * 768 * 64; out += (size_t)l * 49152;
    for (int idx = blockIdx.x * blockDim.x + threadIdx.x; idx < 49152; idx += gridDim.x * blockDim.x) {
        int rec = idx >> 3, j = idx & 7;
        int lane = rec & 63, f = rec >> 6;
        int w = f & 3, ys = f >> 2;
        int y = ys % 3, ks = ys / 3;
        int k = ks * 32 + (lane >> 4) * 8 + j;
        int sec = k & 3, dfeat = k >> 2;
        int d = w * 16 + (lane & 15);
        out[idx] = f2bf(pw[(size_t)(y * 256 + sec * 64 + dfeat) * 64 + d]);
    }
}

// ---------------- per-layer edge kernels (R13 plateau config) ----------------

__launch_bounds__(256, 1)
__global__ void k_gru(const int* __restrict__ src, const int* __restrict__ etype,
                      const u16* __restrict__ nfeat, const u16* __restrict__ equery,
                      const u16* __restrict__ efeat, const float* __restrict__ relw,
                      const u16* __restrict__ wpack,
                      const float* __restrict__ bx, const float* __restrict__ bh,
                      u16* __restrict__ msg) {
    __shared__ u16 sW[32768];
    __shared__ u16 sBuf[4][2048];
    const int tid = threadIdx.x;
    const int lane = tid & 63;
    const int wv = tid >> 6;
    {
        const uint4* gsrc = (const uint4*)wpack;
        uint4* ldst = (uint4*)sW;
        #pragma unroll
        for (int i = 0; i < 16; i++) ldst[tid + i * 256] = gsrc[tid + i * 256];
    }
    __syncthreads();

    const int row = lane & 15, kg = lane >> 4;
    u16* bufA = &sBuf[wv][0];
    u16* bufB = &sBuf[wv][1024];
    float br_[4], bz_[4], bxn_[4], bhn_[4];
    #pragma unroll
    for (int w = 0; w < 4; w++) {
        const int d = w * 16 + row;
        br_[w] = bx[d] + bh[d];
        bz_[w] = bx[64 + d] + bh[64 + d];
        bxn_[w] = bx[128 + d];
        bhn_[w] = bh[128 + d];
    }

    const int NCH = EN / 32;
    const int stride = gridDim.x * 4;
    int ch = blockIdx.x * 4 + wv;
    bf8_t pa0 = {}, pa1 = {}, pb0 = {}, pb1 = {};
    if (ch < NCH) {
        const int s0 = src[ch * 32 + row];
        const int s1 = src[ch * 32 + 16 + row];
        pa0 = *(const bf8_t*)(nfeat + (size_t)s0 * 64 + kg * 8);
        pa1 = *(const bf8_t*)(nfeat + (size_t)s0 * 64 + 32 + kg * 8);
        pb0 = *(const bf8_t*)(nfeat + (size_t)s1 * 64 + kg * 8);
        pb1 = *(const bf8_t*)(nfeat + (size_t)s1 * 64 + 32 + kg * 8);
    }

    for (; ch < NCH; ch += stride) {
        const int base = ch * 32;
        const int e0 = base + row;
        const int e1 = base + 16 + row;
        const int ty0 = etype[e0], ty1 = etype[e1];
        bf8_t af0[4], af1[4];
        {
            bf8_t q0 = *(const bf8_t*)(equery + (size_t)e0 * 64 + kg * 8);
            bf8_t q1 = *(const bf8_t*)(equery + (size_t)e0 * 64 + 32 + kg * 8);
            f4_t na, nb, qa, qb;
            unpk8(pa0, na, nb); unpk8(q0, qa, qb);
            af0[0] = pack8(na + qa, nb + qb);
            unpk8(pa1, na, nb); unpk8(q1, qa, qb);
            af0[1] = pack8(na + qa, nb + qb);
        }
        {
            bf8_t q0 = *(const bf8_t*)(equery + (size_t)e1 * 64 + kg * 8);
            bf8_t q1 = *(const bf8_t*)(equery + (size_t)e1 * 64 + 32 + kg * 8);
            f4_t na, nb, qa, qb;
            unpk8(pb0, na, nb); unpk8(q0, qa, qb);
            af1[0] = pack8(na + qa, nb + qb);
            unpk8(pb1, na, nb); unpk8(q1, qa, qb);
            af1[1] = pack8(na + qa, nb + qb);
        }
        {
            bf8_t x0 = *(const bf8_t*)(efeat + (size_t)e0 * 64 + kg * 8);
            bf8_t x1 = *(const bf8_t*)(efeat + (size_t)e0 * 64 + 32 + kg * 8);
            f4_t r0 = *(const f4_t*)(relw + ty0 * 64 + kg * 8);
            f4_t r1 = *(const f4_t*)(relw + ty0 * 64 + kg * 8 + 4);
            f4_t r2 = *(const f4_t*)(relw + ty0 * 64 + 32 + kg * 8);
            f4_t r3 = *(const f4_t*)(relw + ty0 * 64 + 32 + kg * 8 + 4);
            f4_t ea, eb;
            unpk8(x0, ea, eb);
            af0[2] = pack8(ea * r0, eb * r1);
            unpk8(x1, ea, eb);
            af0[3] = pack8(ea * r2, eb * r3);
        }
        {
            bf8_t x0 = *(const bf8_t*)(efeat + (size_t)e1 * 64 + kg * 8);
            bf8_t x1 = *(const bf8_t*)(efeat + (size_t)e1 * 64 + 32 + kg * 8);
            f4_t r0 = *(const f4_t*)(relw + ty1 * 64 + kg * 8);
            f4_t r1 = *(const f4_t*)(relw + ty1 * 64 + kg * 8 + 4);
            f4_t r2 = *(const f4_t*)(relw + ty1 * 64 + 32 + kg * 8);
            f4_t r3 = *(const f4_t*)(relw + ty1 * 64 + 32 + kg * 8 + 4);
            f4_t ea, eb;
            unpk8(x0, ea, eb);
            af1[2] = pack8(ea * r0, eb * r1);
            unpk8(x1, ea, eb);
            af1[3] = pack8(ea * r2, eb * r3);
        }
        // prefetch next chunk's nfeat gathers
        {
            const int nch = ch + stride;
            if (nch < NCH) {
                const int s0 = src[nch * 32 + row];
                const int s1 = src[nch * 32 + 16 + row];
                pa0 = *(const bf8_t*)(nfeat + (size_t)s0 * 64 + kg * 8);
                pa1 = *(const bf8_t*)(nfeat + (size_t)s0 * 64 + 32 + kg * 8);
                pb0 = *(const bf8_t*)(nfeat + (size_t)s1 * 64 + kg * 8);
                pb1 = *(const bf8_t*)(nfeat + (size_t)s1 * 64 + 32 + kg * 8);
            }
        }
        // stage h into the two wave tiles (swizzled b128 writes)
        *(bf8_t*)&bufA[tswz(row, kg * 8)] = af0[2];
        *(bf8_t*)&bufA[tswz(row, kg * 8 + 32)] = af0[3];
        *(bf8_t*)&bufB[tswz(row, kg * 8)] = af1[2];
        *(bf8_t*)&bufB[tswz(row, kg * 8 + 32)] = af1[3];

        #pragma unroll
        for (int w = 0; w < 4; w++) {
            facc_t ar0 = {0.f, 0.f, 0.f, 0.f}, az0 = ar0, axn0 = ar0, ahn0 = ar0;
            facc_t ar1 = ar0, az1 = ar0, axn1 = ar0, ahn1 = ar0;
            #pragma unroll
            for (int ks = 0; ks < 4; ks++) {
                const int rb = (ks * 16 + w * 4) * 512 + lane * 8;
                bf8_t b0 = *(const bf8_t*)&sW[rb];
                bf8_t b1 = *(const bf8_t*)&sW[rb + 512];
                bf8_t b2 = *(const bf8_t*)&sW[rb + 1024];
                bf8_t b3 = *(const bf8_t*)&sW[rb + 1536];
                ar0  = __builtin_amdgcn_mfma_f32_16x16x32_bf16(af0[ks], b0, ar0, 0, 0, 0);
                ar1  = __builtin_amdgcn_mfma_f32_16x16x32_bf16(af1[ks], b0, ar1, 0, 0, 0);
                az0  = __builtin_amdgcn_mfma_f32_16x16x32_bf16(af0[ks], b1, az0, 0, 0, 0);
                az1  = __builtin_amdgcn_mfma_f32_16x16x32_bf16(af1[ks], b1, az1, 0, 0, 0);
                axn0 = __builtin_amdgcn_mfma_f32_16x16x32_bf16(af0[ks], b2, axn0, 0, 0, 0);
                axn1 = __builtin_amdgcn_mfma_f32_16x16x32_bf16(af1[ks], b2, axn1, 0, 0, 0);
                ahn0 = __builtin_amdgcn_mfma_f32_16x16x32_bf16(af0[ks], b3, ahn0, 0, 0, 0);
                ahn1 = __builtin_amdgcn_mfma_f32_16x16x32_bf16(af1[ks], b3, ahn1, 0, 0, 0);
            }
            #pragma unroll
            for (int rr = 0; rr < 4; rr++) {
                const int idx = tswz(kg * 4 + rr, w * 16 + row);
                {
                    const float r_ = sigm(ar0[rr] + br_[w]);
                    const float z_ = sigm(az0[rr] + bz_[w]);
                    const float n_ = tanh_f(axn0[rr] + bxn_[w] + r_ * (ahn0[rr] + bhn_[w]));
                    const float h_ = bf2f(bufA[idx]);
                    bufA[idx] = f2bf_hw((1.f - z_) * n_ + z_ * h_);
                }
                {
                    const float r_ = sigm(ar1[rr] + br_[w]);
                    const float z_ = sigm(az1[rr] + bz_[w]);
                    const float n_ = tanh_f(axn1[rr] + bxn_[w] + r_ * (ahn1[rr] + bhn_[w]));
                    const float h_ = bf2f(bufB[idx]);
                    bufB[idx] = f2bf_hw((1.f - z_) * n_ + z_ * h_);
                }
            }
        }
        // bulk store: four contiguous 1KB bursts
        const int r8 = lane >> 3, c8 = (lane & 7) * 8;
        bf8_t oA0 = *(const bf8_t*)&bufA[tswz(r8, c8)];
        bf8_t oA1 = *(const bf8_t*)&bufA[tswz(8 + r8, c8)];
        bf8_t oB0 = *(const bf8_t*)&bufB[tswz(r8, c8)];
        bf8_t oB1 = *(const bf8_t*)&bufB[tswz(8 + r8, c8)];
        *(bf8_t*)(msg + (size_t)base * 64 + r8 * 64 + c8) = oA0;
        *(bf8_t*)(msg + (size_t)base * 64 + (8 + r8) * 64 + c8) = oA1;
        *(bf8_t*)(msg + (size_t)(base + 16) * 64 + r8 * 64 + c8) = oB0;
        *(bf8_t*)(msg + (size_t)(base + 16) * 64 + (8 + r8) * 64 + c8) = oB1;
    }
}

__launch_bounds__(256, 1)
__global__ void k_lstm(const int* __restrict__ dst, const u16* __restrict__ nfeat_new,
                       const u16* __restrict__ wpack, const float* __restrict__ bb,
                       const float* __restrict__ g_ln, const float* __restrict__ b_ln,
                       u16* __restrict__ efeat, u16* __restrict__ equery) {
    __shared__ u16 sW[32768];
    __shared__ u16 sBuf[4][1024];
    const int tid = threadIdx.x;
    const int lane = tid & 63;
    const int wv = tid >> 6;
    {
        const uint4* gsrc = (const uint4*)wpack;
        uint4* ldst = (uint4*)sW;
        #pragma unroll
        for (int i = 0; i < 16; i++) ldst[tid + i * 256] = gsrc[tid + i * 256];
    }
    __syncthreads();

    const int row = lane & 15, kg = lane >> 4;
    u16* buf = &sBuf[wv][0];
    float lgv[4], lbv[4];
    #pragma unroll
    for (int w = 0; w < 4; w++) { lgv[w] = g_ln[w * 16 + row]; lbv[w] = b_ln[w * 16 + row]; }

    const int NCH = EN / 16;
    const int stride = gridDim.x * 4;
    int ch = blockIdx.x * 4 + wv;
    bf8_t pn0 = {}, pn1 = {}, pe0 = {}, pe1 = {};
    if (ch < NCH) {
        const int de = dst[ch * 16 + row];
        pn0 = *(const bf8_t*)(nfeat_new + (size_t)de * 64 + kg * 8);
        pn1 = *(const bf8_t*)(nfeat_new + (size_t)de * 64 + 32 + kg * 8);
        pe0 = *(const bf8_t*)(efeat + (size_t)(ch * 16 + row) * 64 + kg * 8);
        pe1 = *(const bf8_t*)(efeat + (size_t)(ch * 16 + row) * 64 + 32 + kg * 8);
    }

    for (; ch < NCH; ch += stride) {
        const int base = ch * 16;
        const int e = base + row;
        bf8_t af[4];
        af[0] = pn0;
        af[1] = pn1;
        af[2] = pe0;
        af[3] = pe1;
        // stage equery-old into the wave tile (swizzled)
        {
            bf8_t q0 = *(const bf8_t*)(equery + (size_t)e * 64 + kg * 8);
            bf8_t q1 = *(const bf8_t*)(equery + (size_t)e * 64 + 32 + kg * 8);
            *(bf8_t*)&buf[tswz(row, kg * 8)] = q0;
            *(bf8_t*)&buf[tswz(row, kg * 8 + 32)] = q1;
        }
        // prefetch next chunk's nfeat_new gather (hidden under the gate loop)
        {
            const int nch = ch + stride;
            if (nch < NCH) {
                const int de = dst[nch * 16 + row];
                pn0 = *(const bf8_t*)(nfeat_new + (size_t)de * 64 + kg * 8);
                pn1 = *(const bf8_t*)(nfeat_new + (size_t)de * 64 + 32 + kg * 8);
            }
        }

        // hc[w][rr] = packed (bf16 hh, bf16 cc); LN sums stay exact f32
        unsigned hc[4][4];
        float sh[4] = {0, 0, 0, 0}, sh2[4] = {0, 0, 0, 0};
        float sc[4] = {0, 0, 0, 0}, sc2[4] = {0, 0, 0, 0};

        #pragma unroll
        for (int w = 0; w < 4; w++) {
            facc_t ai = {0.f, 0.f, 0.f, 0.f}, afv = ai, ag = ai, ao = ai;
            #pragma unroll
            for (int ks = 0; ks < 4; ks++) {
                const int rb = (ks * 16 + w * 4) * 512 + lane * 8;
                bf8_t b0 = *(const bf8_t*)&sW[rb];
                bf8_t b1 = *(const bf8_t*)&sW[rb + 512];
                bf8_t b2 = *(const bf8_t*)&sW[rb + 1024];
                bf8_t b3 = *(const bf8_t*)&sW[rb + 1536];
                ai  = __builtin_amdgcn_mfma_f32_16x16x32_bf16(af[ks], b0, ai, 0, 0, 0);
                afv = __builtin_amdgcn_mfma_f32_16x16x32_bf16(af[ks], b1, afv, 0, 0, 0);
                ag  = __builtin_amdgcn_mfma_f32_16x16x32_bf16(af[ks], b2, ag, 0, 0, 0);
                ao  = __builtin_amdgcn_mfma_f32_16x16x32_bf16(af[ks], b3, ao, 0, 0, 0);
            }
            const int d = w * 16 + row;
            const float bi = bb[d], bf_ = bb[64 + d], bg = bb[128 + d], bo = bb[192 + d];
            #pragma unroll
            for (int rr = 0; rr < 4; rr++) {
                const int idx = tswz(kg * 4 + rr, d);
                const float eq = bf2f(buf[idx]);
                const float ci = sigm(ai[rr] + bi);
                const float cf = sigm(afv[rr] + bf_);
                const float cg = tanh_f(ag[rr] + bg);
                const float co = sigm(ao[rr] + bo);
                const float c_ = cf * eq + ci * cg;
                const float h_ = co * tanh_f(c_);
                hc[w][rr] = cvtpk(h_, c_);
                sh[rr] += h_; sh2[rr] += h_ * h_;
                sc[rr] += c_; sc2[rr] += c_ * c_;
            }
        }
        #pragma unroll
        for (int off = 1; off < 16; off <<= 1) {
            #pragma unroll
            for (int rr = 0; rr < 4; rr++) {
                sh[rr] += __shfl_xor(sh[rr], off, 64);
                sh2[rr] += __shfl_xor(sh2[rr], off, 64);
                sc[rr] += __shfl_xor(sc[rr], off, 64);
                sc2[rr] += __shfl_xor(sc2[rr], off, 64);
            }
        }
        float hm[4], hrs[4], cm[4], crs[4];
        #pragma unroll
        for (int rr = 0; rr < 4; rr++) {
            hm[rr] = sh[rr] * (1.f / 64.f);
            hrs[rr] = rsqrtf(sh2[rr] * (1.f / 64.f) - hm[rr] * hm[rr] + EPS_);
            cm[rr] = sc[rr] * (1.f / 64.f);
            crs[rr] = rsqrtf(sc2[rr] * (1.f / 64.f) - cm[rr] * cm[rr] + EPS_);
        }
        // prefetch next chunk's efeat rows (hidden under the two output passes)
        {
            const int nch = ch + stride;
            if (nch < NCH) {
                const size_t ne = (size_t)(nch * 16 + row) * 64;
                pe0 = *(const bf8_t*)(efeat + ne + kg * 8);
                pe1 = *(const bf8_t*)(efeat + ne + 32 + kg * 8);
            }
        }
        // pass 1: equery-new in place (cc = hi half of hc), bulk store
        #pragma unroll
        for (int w = 0; w < 4; w++) {
            #pragma unroll
            for (int rr = 0; rr < 4; rr++) {
                const int idx = tswz(kg * 4 + rr, w * 16 + row);
                const float eqo = bf2f(buf[idx]);
                const float c_ = bf2f((u16)(hc[w][rr] >> 16));
                buf[idx] = f2bf_hw(eqo + (c_ - cm[rr]) * crs[rr] * lgv[w] + lbv[w]);
            }
        }
        {
            const int r8 = lane >> 3, c8 = (lane & 7) * 8;
            bf8_t o0 = *(const bf8_t*)&buf[tswz(r8, c8)];
            bf8_t o1 = *(const bf8_t*)&buf[tswz(8 + r8, c8)];
            *(bf8_t*)(equery + (size_t)base * 64 + r8 * 64 + c8) = o0;
            *(bf8_t*)(equery + (size_t)base * 64 + (8 + r8) * 64 + c8) = o1;
        }
        // restage efeat-old (still in af[2..3])
        *(bf8_t*)&buf[tswz(row, kg * 8)] = af[2];
        *(bf8_t*)&buf[tswz(row, kg * 8 + 32)] = af[3];
        // pass 2: efeat-new in place (hh = lo half of hc), bulk store
        #pragma unroll
        for (int w = 0; w < 4; w++) {
            #pragma unroll
            for (int rr = 0; rr < 4; rr++) {
                const int idx = tswz(kg * 4 + rr, w * 16 + row);
                const float efo = bf2f(buf[idx]);
                const float h_ = bf2f((u16)(hc[w][rr] & 0xFFFFu));
                buf[idx] = f2bf_hw(efo + (h_ - hm[rr]) * hrs[rr] * lgv[w] + lbv[w]);
            }
        }
        {
            const int r8 = lane >> 3, c8 = (lane & 7) * 8;
            bf8_t o0 = *(const bf8_t*)&buf[tswz(r8, c8)];
            bf8_t o1 = *(const bf8_t*)&buf[tswz(8 + r8, c8)];
            *(bf8_t*)(efeat + (size_t)base * 64 + r8 * 64 + c8) = o0;
            *(bf8_t*)(efeat + (size_t)base * 64 + (8 + r8) * 64 + c8) = o1;
        }
    }
}

// k_node: unchanged structure (msg reads are wave-contiguous full lines).
__launch_bounds__(256)
__global__ void k_node(const int* __restrict__ row_ptr, const int* __restrict__ eid,
                       const u16* __restrict__ msg, const float* __restrict__ avg_sum,
                       const u16* __restrict__ wpack, const float* __restrict__ pb,
                       const float* __restrict__ g_ln, const float* __restrict__ b_ln,
                       u16* __restrict__ nfeat, u16* __restrict__ nfeat_new) {
    __shared__ u16 sAgg[16 * 280];
    __shared__ float sS[16], sT[16];
    __shared__ float sRed[4][16][2];
    const int lane = threadIdx.x & 63;
    const int w = threadIdx.x >> 6;
    const int base = blockIdx.x * 16;
    const float avg = avg_sum[0] * (1.f / (float)NN);

    bf8_t bw[8][3];
    #pragma unroll
    for (int ks = 0; ks < 8; ks++) {
        #pragma unroll
        for (int y = 0; y < 3; y++)
            bw[ks][y] = ((const bf8_t*)wpack)[((ks * 3 + y) * 4 + w) * 64 + lane];
    }

    float samp[4], satt[4];
    #pragma unroll
    for (int q = 0; q < 4; q++) {
        const int m = w * 4 + q;
        const int v = base + m;
        const int rs = row_ptr[v], re = row_ptr[v + 1];
        float s = 0.f, s2 = 0.f, mx = -INFINITY, mn = INFINITY;
        for (int i = rs; i < re; i++) {
            const int e = eid[i];
            const float mv = bf2f(msg[(size_t)e * 64 + lane]);
            s += mv; s2 += mv * mv; mx = fmaxf(mx, mv); mn = fminf(mn, mv);
        }
        const float deg = (float)(re - rs);
        const float dsafe = fmaxf(deg, 1.f);
        const float mean = s / dsafe;
        const float sq = s2 / dsafe;
        const bool has = (re - rs) > 0;
        const float amx = has ? mx : 0.f;
        const float amn = has ? mn : 0.f;
        const float astd = sqrtf(fmaxf(sq - mean * mean, 0.f) + EPS_);
        uint2 pk;
        pk.x = cvtpk(mean, amx);
        pk.y = cvtpk(amn, astd);
        *(uint2*)&sAgg[m * 280 + lane * 4] = pk;
        const float ld = logf(deg + 1.f);
        samp[q] = ld / avg;
        satt[q] = ld > 0.f ? avg / fmaxf(ld, EPS_) : 0.f;
    }
    if (lane == 0) {
        #pragma unroll
        for (int q = 0; q < 4; q++) { sS[w * 4 + q] = samp[q]; sT[w * 4 + q] = satt[q]; }
    }
    __syncthreads();

    facc_t c0 = {0.f, 0.f, 0.f, 0.f}, c1 = c0, c2 = c0;
    const int arow = lane & 15, acol = (lane >> 4) * 8;
    #pragma unroll
    for (int ks = 0; ks < 8; ks++) {
        bf8_t af = *(const bf8_t*)&sAgg[arow * 280 + ks * 32 + acol];
        c0 = __builtin_amdgcn_mfma_f32_16x16x32_bf16(af, bw[ks][0], c0, 0, 0, 0);
        c1 = __builtin_amdgcn_mfma_f32_16x16x32_bf16(af, bw[ks][1], c1, 0, 0, 0);
        c2 = __builtin_amdgcn_mfma_f32_16x16x32_bf16(af, bw[ks][2], c2, 0, 0, 0);
    }

    const int d = w * 16 + (lane & 15);
    const float pbl = pb[d], lg = g_ln[d], lb = b_ln[d];
    float nf[4];
    #pragma unroll
    for (int rr = 0; rr < 4; rr++) {
        const int m = (lane >> 4) * 4 + rr;
        nf[rr] = pbl + c0[rr] + sS[m] * c1[rr] + sT[m] * c2[rr];
        nfeat_new[(size_t)(base + m) * 64 + d] = f2bf_hw(nf[rr]);
    }
    float ps[4], ps2[4];
    #pragma unroll
    for (int rr = 0; rr < 4; rr++) { ps[rr] = nf[rr]; ps2[rr] = nf[rr] * nf[rr]; }
    #pragma unroll
    for (int off = 1; off < 16; off <<= 1) {
        #pragma unroll
        for (int rr = 0; rr < 4; rr++) {
            ps[rr] += __shfl_xor(ps[rr], off, 64);
            ps2[rr] += __shfl_xor(ps2[rr], off, 64);
        }
    }
    if ((lane & 15) == 0) {
        #pragma unroll
        for (int rr = 0; rr < 4; rr++) {
            const int m = (lane >> 4) * 4 + rr;
            sRed[w][m][0] = ps[rr];
            sRed[w][m][1] = ps2[rr];
        }
    }
    __syncthreads();
    #pragma unroll
    for (int rr = 0; rr < 4; rr++) {
        const int m = (lane >> 4) * 4 + rr;
        float ts = 0.f, ts2 = 0.f;
        #pragma unroll
        for (int w2 = 0; w2 < 4; w2++) { ts += sRed[w2][m][0]; ts2 += sRed[w2][m][1]; }
        const float mean = ts * (1.f / 64.f);
        const float var = ts2 * (1.f / 64.f) - mean * mean;
        const size_t off = (size_t)(base + m) * 64 + d;
        nfeat[off] = f2bf_hw(bf2f(nfeat[off]) + (nf[rr] - mean) * rsqrtf(var + EPS_) * lg + lb);
    }
}

__global__ void k_snap(const int* __restrict__ tgt, const int* __restrict__ src,
                       const u16* __restrict__ efeat, const u16* __restrict__ equery,
                       const u16* __restrict__ nfeat,
                       float* jk_e, float* jk_q, float* jk_n) {
    int t = blockIdx.x, d = threadIdx.x;
    int e = tgt[t];
    jk_e[t * 64 + d] = bf2f(efeat[(size_t)e * 64 + d]);
    jk_q[t * 64 + d] = bf2f(equery[(size_t)e * 64 + d]);
    int v = src[e];
    jk_n[t * 64 + d] = bf2f(nfeat[v * 64 + d]);
}

// ---------------- output head ----------------

__global__ void k_jk(const float* __restrict__ jk_e, const float* __restrict__ jk_q, const float* __restrict__ jk_n,
                     const float* __restrict__ ejk_w, const float* __restrict__ ejk_b,
                     const float* __restrict__ qjk_w, const float* __restrict__ qjk_b,
                     const float* __restrict__ njk_w, const float* __restrict__ njk_b,
                     float* ejk_o, float* qjk_o, float* njk_o) {
    int t = blockIdx.x, d = threadIdx.x;
    float ae = ejk_b[d], aq = qjk_b[d], an_ = njk_b[d];
    for (int l = 0; l < 3; l++) {
        for (int dd = 0; dd < 64; dd++) {
            int k = l * 64 + dd;
            ae += jk_e[(l * 64 + t) * 64 + dd] * ejk_w[k * 64 + d];
            aq += jk_q[(l * 64 + t) * 64 + dd] * qjk_w[k * 64 + d];
            an_ += jk_n[(l * 64 + t) * 64 + dd] * njk_w[k * 64 + d];
        }
    }
    ejk_o[t * 64 + d] = ae;
    qjk_o[t * 64 + d] = aq;
    njk_o[t * 64 + d] = an_;
}

__global__ void k_final(const float* __restrict__ ejk_o, const float* __restrict__ qjk_o,
                        const float* __restrict__ njk_o,
                        const float* __restrict__ fc_w, const float* __restrict__ fc_b,
                        float* out) {
    int b = blockIdx.x, d = threadIdx.x;
    int t0 = 2 * b, t1 = 2 * b + 1;
    float r = ejk_o[t0 * 64 + d] * fc_w[d] + qjk_o[t0 * 64 + d] * fc_w[64 + d]
            + njk_o[t0 * 64 + d] * fc_w[128 + d] + njk_o[t1 * 64 + d] * fc_w[192 + d];
    float lf = ejk_o[t1 * 64 + d] * fc_w[d] + qjk_o[t1 * 64 + d] * fc_w[64 + d]
             + njk_o[t1 * 64 + d] * fc_w[128 + d] + njk_o[t0 * 64 + d] * fc_w[192 + d];
    #pragma unroll
    for (int off = 32; off > 0; off >>= 1) { r += __shfl_xor(r, off, 64); lf += __shfl_xor(lf, off, 64); }
    if (d == 0) out[b] = fmaxf(r + fc_b[0], lf + fc_b[0]);
}

// ---------------- host launcher ----------------

extern "C" void kernel_launch(void* const* d_in, const int* in_sizes, int n_in,
                              void* d_out, int out_size, void* d_ws, size_t ws_size,
                              hipStream_t stream) {
    const int* src   = (const int*)d_in[0];
    const int* dst   = (const int*)d_in[1];
    const int* etype = (const int*)d_in[2];
    const int* egid  = (const int*)d_in[3];
    const int* tgt   = (const int*)d_in[4];
    const float* query_emb = (const float*)d_in[6];
    const float* eqp_w = (const float*)d_in[7];
    const float* eqp_b = (const float*)d_in[8];
    const float* rel_w = (const float*)d_in[9];
    const float* gru_wx = (const float*)d_in[10];
    const float* gru_wh = (const float*)d_in[11];
    const float* gru_bx = (const float*)d_in[12];
    const float* gru_bh = (const float*)d_in[13];
    const float* pna_w = (const float*)d_in[14];
    const float* pna_b = (const float*)d_in[15];
    const float* lstm_wx = (const float*)d_in[16];
    const float* lstm_wh = (const float*)d_in[17];
    const float* lstm_b = (const float*)d_in[18];
    const float* ln_g = (const float*)d_in[19];
    const float* ln_b = (const float*)d_in[20];
    const float* ejk_w = (const float*)d_in[21];
    const float* ejk_b = (const float*)d_in[22];
    const float* njk_w = (const float*)d_in[23];
    const float* njk_b = (const float*)d_in[24];
    const float* qjk_w = (const float*)d_in[25];
    const float* qjk_b = (const float*)d_in[26];
    const float* fc_w = (const float*)d_in[27];
    const float* fc_b = (const float*)d_in[28];

    u16* q16 = (u16*)d_ws;
    u16* equery = q16;     q16 += (size_t)EN * 64;
    u16* efeat = q16;      q16 += (size_t)EN * 64;
    u16* msg = q16;        q16 += (size_t)EN * 64;
    u16* nfeat = q16;      q16 += (size_t)NN * 64;
    u16* nfeat_new = q16;  q16 += (size_t)NN * 64;
    u16* wpg = q16;        q16 += 3 * 32768;
    u16* wpl = q16;        q16 += 3 * 32768;
    u16* wpp = q16;        q16 += 3 * 49152;
    u16* gates0 = q16;     q16 += (size_t)NN * 256;
    u16* msg_row = q16;    q16 += 32 * 64;
    q16 += 32;  // alignment pad
    float* p = (float*)q16;
    float* tgt_q = p;     p += 64 * 64;
    float* eq_g = p;      p += 32 * 64;
    float* jk_e = p;      p += 3 * 64 * 64;
    float* jk_q = p;      p += 3 * 64 * 64;
    float* jk_n = p;      p += 3 * 64 * 64;
    float* ejk_o = p;     p += 64 * 64;
    float* qjk_o = p;     p += 64 * 64;
    float* njk_o = p;     p += 64 * 64;
    float* avg_sum = p;   p += 64;
    int* ip = (int*)p;
    int* row_ptr = ip; ip += NN + 1;
    int* fillp = ip;   ip += NN;
    int* cnt = ip;     ip += NN;
    int* outcnt = ip;  ip += NN;
    int* eid = ip;     ip += EN;
    int* bsum = ip;    ip += 64;
    int* boff = ip;    ip += 64;
    if ((size_t)((char*)ip - (char*)d_ws) > ws_size) return;

    k_init<<<4096, 256, 0, stream>>>(efeat, nfeat, cnt, outcnt, avg_sum);
    k_count<<<1024, 256, 0, stream>>>(src, dst, cnt, outcnt);
    k_scan1<<<40, 1024, 0, stream>>>(cnt, row_ptr, bsum);
    k_scan2<<<1, 64, 0, stream>>>(bsum, boff, row_ptr);
    k_scan3<<<40, 1024, 0, stream>>>(row_ptr, fillp, boff);
    k_fill<<<1024, 256, 0, stream>>>(dst, fillp, eid);
    k_avg<<<(NN + 255) / 256, 256, 0, stream>>>(outcnt, avg_sum);
    k_tgt<<<64, 64, 0, stream>>>(tgt, etype, query_emb, tgt_q, efeat);
    k_eqg<<<32, 64, 0, stream>>>(tgt_q, eqp_w, eqp_b, eq_g);
    k_equery<<<8192, 256, 0, stream>>>(egid, eq_g, equery);
    k_pack_gru<<<dim3(16, 3), 256, 0, stream>>>(gru_wx, gru_wh, wpg);
    k_pack_lstm<<<dim3(16, 3), 256, 0, stream>>>(lstm_wx, lstm_wh, wpl);
    k_pack_pna<<<dim3(24, 3), 256, 0, stream>>>(pna_w, wpp);

    for (int l = 0; l < 3; l++) {
        if (l == 0) {
            k_gru0_rows<<<32, 64, 0, stream>>>(eq_g, gru_wx, gru_bx, gru_bh, msg_row);
            k_gru0_scatter<<<4096, 256, 0, stream>>>(egid, msg_row, msg);
            k_gru0_fix<<<64, 64, 0, stream>>>(tgt, etype, equery, efeat, rel_w,
                gru_wx, gru_wh, gru_bx, gru_bh, msg);
        } else {
            k_gru<<<512, 256, 0, stream>>>(src, etype, nfeat, equery, efeat,
                rel_w + (size_t)l * NR * 64, wpg + (size_t)l * 32768,
                gru_bx + (size_t)l * 192, gru_bh + (size_t)l * 192, msg);
        }
        k_node<<<NN / 16, 256, 0, stream>>>(row_ptr, eid, msg, avg_sum,
            wpp + (size_t)l * 49152, pna_b + (size_t)l * 64,
            ln_g + (size_t)l * 64, ln_b + (size_t)l * 64, nfeat, nfeat_new);
        if (l == 0) {
            // layer-0 LSTM: gates depend only on dst node (efeat==0 except targets)
            k_lstm0_gates<<<512, 256, 0, stream>>>(nfeat_new, wpl, lstm_b, gates0);
            k_lstm0_apply<<<2048, 256, 0, stream>>>(dst, gates0, eq_g, ln_g, ln_b, efeat, equery);
            k_lstm0_fix<<<64, 64, 0, stream>>>(tgt, dst, nfeat_new, lstm_wx, lstm_wh,
                lstm_b, ln_g, ln_b, efeat, equery);
        } else {
            k_lstm<<<512, 256, 0, stream>>>(dst, nfeat_new, wpl + (size_t)l * 32768,
                lstm_b + (size_t)l * 256,
                ln_g + (size_t)l * 64, ln_b + (size_t)l * 64, efeat, equery);
        }
        k_snap<<<64, 64, 0, stream>>>(tgt, src, efeat, equery, nfeat,
            jk_e + l * 4096, jk_q + l * 4096, jk_n + l * 4096);
    }

    k_jk<<<64, 64, 0, stream>>>(jk_e, jk_q, jk_n, ejk_w, ejk_b, qjk_w, qjk_b, njk_w, njk_b,
                                ejk_o, qjk_o, njk_o);
    k_final<<<32, 64, 0, stream>>>(ejk_o, qjk_o, njk_o, fc_w, fc_b, (float*)d_out);
}

// Round 20
// 746.650 us; speedup vs baseline: 1.0278x; 1.0278x over previous
//
#include <hip/hip_runtime.h>
#include <math.h>

#define EN 256000
#define NN 40000
#define NR 474
#define EPS_ 1e-5f

typedef unsigned short u16;
typedef __attribute__((ext_vector_type(4))) float f4_t;
typedef __attribute__((ext_vector_type(8))) short bf8_t;
typedef __attribute__((ext_vector_type(4))) float facc_t;

__device__ __forceinline__ float sigm(float x) { return 1.f / (1.f + __expf(-x)); }
__device__ __forceinline__ float tanh_f(float x) { float e = __expf(2.f * x); return 1.f - 2.f / (e + 1.f); }

__device__ __forceinline__ u16 f2bf(float f) {
    unsigned u = __float_as_uint(f);
    return (u16)((u + 0x7FFFu + ((u >> 16) & 1u)) >> 16);
}
__device__ __forceinline__ unsigned cvtpk(float lo, float hi) {
    unsigned r;
    asm("v_cvt_pk_bf16_f32 %0, %1, %2" : "=v"(r) : "v"(lo), "v"(hi));
    return r;
}
__device__ __forceinline__ u16 f2bf_hw(float v) { return (u16)cvtpk(v, v); }
__device__ __forceinline__ float bf2f(u16 u) { return __uint_as_float(((unsigned)u) << 16); }

__device__ __forceinline__ bf8_t pack8(f4_t a, f4_t b) {
    union { unsigned u[4]; bf8_t v; } r;
    r.u[0] = cvtpk(a[0], a[1]);
    r.u[1] = cvtpk(a[2], a[3]);
    r.u[2] = cvtpk(b[0], b[1]);
    r.u[3] = cvtpk(b[2], b[3]);
    return r.v;
}
__device__ __forceinline__ void unpk8(bf8_t v, f4_t& a, f4_t& b) {
    a[0] = bf2f((u16)v[0]); a[1] = bf2f((u16)v[1]); a[2] = bf2f((u16)v[2]); a[3] = bf2f((u16)v[3]);
    b[0] = bf2f((u16)v[4]); b[1] = bf2f((u16)v[5]); b[2] = bf2f((u16)v[6]); b[3] = bf2f((u16)v[7]);
}

// swizzled u16 index into a 16x64 wave tile (see round-11 analysis)
__device__ __forceinline__ int tswz(int r, int u) {
    return r * 64 + (u ^ (((r >> 2) & 3) << 4));
}

// ---------------- init / graph prep ----------------

__global__ void k_init(u16* efeat, u16* nfeat, int* cnt, int* outcnt, float* avg_sum) {
    long total = (long)EN * 32;
    unsigned* ef = (unsigned*)efeat;
    unsigned* nf = (unsigned*)nfeat;
    for (long i = blockIdx.x * (long)blockDim.x + threadIdx.x; i < total; i += (long)gridDim.x * blockDim.x) {
        ef[i] = 0u;
        if (i < (long)NN * 32) nf[i] = 0u;
        if (i < NN) { cnt[i] = 0; outcnt[i] = 0; }
        if (i == 0) avg_sum[0] = 0.f;
    }
}

__global__ void k_count(const int* __restrict__ src, const int* __restrict__ dst, int* cnt, int* outcnt) {
    for (int e = blockIdx.x * blockDim.x + threadIdx.x; e < EN; e += gridDim.x * blockDim.x) {
        atomicAdd(&cnt[dst[e]], 1);
        atomicAdd(&outcnt[src[e]], 1);
    }
}

// 3-kernel device-wide exclusive scan
__global__ void k_scan1(const int* __restrict__ cnt, int* __restrict__ row_ptr, int* __restrict__ bsum) {
    __shared__ int tmp[1024];
    const int b = blockIdx.x, t = threadIdx.x;
    const int idx = b * 1024 + t;
    const int v = (idx < NN) ? cnt[idx] : 0;
    tmp[t] = v;
    __syncthreads();
    for (int off = 1; off < 1024; off <<= 1) {
        int u = (t >= off) ? tmp[t - off] : 0;
        __syncthreads();
        tmp[t] += u;
        __syncthreads();
    }
    if (idx < NN) row_ptr[idx] = tmp[t] - v;
    if (t == 1023) bsum[b] = tmp[t];
}

__global__ void k_scan2(const int* __restrict__ bsum, int* __restrict__ boff, int* __restrict__ row_ptr) {
    const int t = threadIdx.x;
    const int v = (t < 40) ? bsum[t] : 0;
    int s = v;
    #pragma unroll
    for (int off = 1; off < 64; off <<= 1) {
        int u = __shfl_up(s, off, 64);
        if (t >= off) s += u;
    }
    if (t < 40) boff[t] = s - v;
    if (t == 63) row_ptr[NN] = s;
}

__global__ void k_scan3(int* __restrict__ row_ptr, int* __restrict__ fillp, const int* __restrict__ boff) {
    const int idx = blockIdx.x * 1024 + threadIdx.x;
    if (idx < NN) {
        const int r = row_ptr[idx] + boff[blockIdx.x];
        row_ptr[idx] = r;
        fillp[idx] = r;
    }
}

__global__ void k_fill(const int* __restrict__ dst, int* fillp, int* eid) {
    for (int e = blockIdx.x * blockDim.x + threadIdx.x; e < EN; e += gridDim.x * blockDim.x) {
        int pos = atomicAdd(&fillp[dst[e]], 1);
        eid[pos] = e;
    }
}

__global__ void k_avg(const int* __restrict__ outcnt, float* __restrict__ avg_sum) {
    int n = blockIdx.x * blockDim.x + threadIdx.x;
    float v = 0.f;
    if (n < NN) v = logf((float)outcnt[n] + 1.f);
    #pragma unroll
    for (int off = 32; off > 0; off >>= 1) v += __shfl_xor(v, off, 64);
    if ((threadIdx.x & 63) == 0) atomicAdd(avg_sum, v);
}

__global__ void k_tgt(const int* __restrict__ tgt, const int* __restrict__ etype,
                      const float* __restrict__ query_emb, float* tgt_q, u16* efeat) {
    int t = blockIdx.x, d = threadIdx.x;
    int e = tgt[t];
    int r = etype[e];
    float v = query_emb[r * 64 + d];
    tgt_q[t * 64 + d] = v;
    efeat[(size_t)e * 64 + d] = f2bf(v);
}

__global__ void k_eqg(const float* __restrict__ tgt_q, const float* __restrict__ eqp_w,
                      const float* __restrict__ eqp_b, float* eq_g) {
    int g = blockIdx.x, d = threadIdx.x;
    float acc = eqp_b[d];
    for (int k = 0; k < 128; k++) {
        float a = tgt_q[(2 * g + (k >> 6)) * 64 + (k & 63)];
        acc += a * eqp_w[k * 64 + d];
    }
    eq_g[g * 64 + d] = acc;
}

__global__ void k_equery(const int* __restrict__ egid, const float* __restrict__ eq_g, u16* equery) {
    long total = (long)EN * 64;
    for (long i = blockIdx.x * (long)blockDim.x + threadIdx.x; i < total; i += (long)gridDim.x * blockDim.x) {
        int e = (int)(i >> 6), d = (int)(i & 63);
        equery[i] = f2bf(eq_g[egid[e] * 64 + d]);
    }
}

// ---------------- layer-0 GRU specialization ----------------

__global__ void k_gru0_rows(const float* __restrict__ eq_g, const float* __restrict__ wx,
                            const float* __restrict__ bx, const float* __restrict__ bh,
                            u16* __restrict__ msg_row) {
    const int g = blockIdx.x, d = threadIdx.x;  // 32 x 64
    float ar = bx[d], az = bx[64 + d], an = bx[128 + d];
    for (int k = 0; k < 64; k++) {
        const float x = bf2f(f2bf(eq_g[g * 64 + k]));
        ar += x * wx[k * 192 + d];
        az += x * wx[k * 192 + 64 + d];
        an += x * wx[k * 192 + 128 + d];
    }
    const float r = sigm(ar + bh[d]);
    const float z = sigm(az + bh[64 + d]);
    const float n = tanh_f(an + r * bh[128 + d]);
    msg_row[g * 64 + d] = f2bf((1.f - z) * n);
}

__global__ void k_gru0_scatter(const int* __restrict__ egid, const u16* __restrict__ msg_row,
                               u16* __restrict__ msg) {
    long total = (long)EN * 32;
    const unsigned* mr = (const unsigned*)msg_row;
    unsigned* m = (unsigned*)msg;
    for (long i = blockIdx.x * (long)blockDim.x + threadIdx.x; i < total; i += (long)gridDim.x * blockDim.x) {
        const int e = (int)(i >> 5);
        const int dd = (int)(i & 31);
        m[i] = mr[egid[e] * 32 + dd];
    }
}

__global__ void k_gru0_fix(const int* __restrict__ tgt, const int* __restrict__ etype,
                           const u16* __restrict__ equery, const u16* __restrict__ efeat,
                           const float* __restrict__ relw,
                           const float* __restrict__ wx, const float* __restrict__ wh,
                           const float* __restrict__ bx, const float* __restrict__ bh,
                           u16* __restrict__ msg) {
    const int t = blockIdx.x, d = threadIdx.x;  // 64 x 64
    const int e = tgt[t];
    const int ty = etype[e];
    float ar = bx[d], az = bx[64 + d], an = bx[128 + d];
    float br = bh[d], bz = bh[64 + d], bn = bh[128 + d];
    for (int k = 0; k < 64; k++) {
        const float x = bf2f(equery[(size_t)e * 64 + k]);
        const float h = bf2f(efeat[(size_t)e * 64 + k]) * relw[ty * 64 + k];
        ar += x * wx[k * 192 + d];       br += h * wh[k * 192 + d];
        az += x * wx[k * 192 + 64 + d];  bz += h * wh[k * 192 + 64 + d];
        an += x * wx[k * 192 + 128 + d]; bn += h * wh[k * 192 + 128 + d];
    }
    const float r = sigm(ar + br);
    const float z = sigm(az + bz);
    const float n = tanh_f(an + r * bn);
    const float h_ = bf2f(efeat[(size_t)e * 64 + d]) * relw[ty * 64 + d];
    msg[(size_t)e * 64 + d] = f2bf_hw((1.f - z) * n + z * h_);
}

// ---------------- weight packing for MFMA ----------------
// GRU pack, 3 sections (r, z, n): the n-column is Wx_n for k<64 and Wh_n for
// k>=64 (the old 4-section pack zero-padded both -> 25% wasted LDS + MFMAs).
// rec rw = (ks*4+w)*3 + g; elem j: W[k][c], k = ks*32+(lane>>4)*8+j,
// c per section; d = w*16+(lane&15). 48KB total -> k_gru block = 64KB LDS.

__global__ void k_pack_gru(const float* __restrict__ wx, const float* __restrict__ wh,
                           u16* __restrict__ out) {
    int l = blockIdx.y;
    wx += (size_t)l * 64 * 192; wh += (size_t)l * 64 * 192; out += (size_t)l * 24576;
    for (int idx = blockIdx.x * blockDim.x + threadIdx.x; idx < 24576; idx += gridDim.x * blockDim.x) {
        int rec = idx >> 3, j = idx & 7;
        int lane = rec & 63, rw = rec >> 6;
        int g = rw % 3, ksw = rw / 3;
        int w = ksw & 3, ks = ksw >> 2;
        int k = ks * 32 + (lane >> 4) * 8 + j;
        int d = w * 16 + (lane & 15);
        float v;
        if (g == 0)      v = k < 64 ? wx[k * 192 + d]       : wh[(k - 64) * 192 + d];
        else if (g == 1) v = k < 64 ? wx[k * 192 + 64 + d]  : wh[(k - 64) * 192 + 64 + d];
        else             v = k < 64 ? wx[k * 192 + 128 + d] : wh[(k - 64) * 192 + 128 + d];
        out[idx] = f2bf(v);
    }
}

__global__ void k_pack_lstm(const float* __restrict__ wx, const float* __restrict__ wh,
                            u16* __restrict__ out) {
    int l = blockIdx.y;
    wx += (size_t)l * 64 * 256; wh += (size_t)l * 64 * 256; out += (size_t)l * 32768;
    for (int idx = blockIdx.x * blockDim.x + threadIdx.x; idx < 32768; idx += gridDim.x * blockDim.x) {
        int rec = idx >> 3, j = idx & 7;
        int lane = rec & 63, ksnt = rec >> 6;
        int nt = ksnt & 15, ks = ksnt >> 4;
        int k = ks * 32 + (lane >> 4) * 8 + j;
        int g = nt & 3, d = (nt >> 2) * 16 + (lane & 15);
        float v = k < 64 ? wx[k * 256 + g * 64 + d] : wh[(k - 64) * 256 + g * 64 + d];
        out[idx] = f2bf(v);
    }
}

__global__ void k_pack_pna(const float* __restrict__ pw, u16* __restrict__ out) {
    int l = blockIdx.y;
    pw += (size_t)l * 768 * 64; out += (size_t)l * 49152;
    for (int idx = blockIdx.x * blockDim.x + threadIdx.x; idx < 49152; idx += gridDim.x * blockDim.x) {
        int rec = idx >> 3, j = idx & 7;
        int lane = rec & 63, f = rec >> 6;
        int w = f & 3, ys = f >> 2;
        int y = ys % 3, ks = ys / 3;
        int k = ks * 32 + (lane >> 4) * 8 + j;
        int sec = k & 3, dfeat = k >> 2;
        int d = w * 16 + (lane & 15);
        out[idx] = f2bf(pw[(size_t)(y * 256 + sec * 64 + dfeat) * 64 + d]);
    }
}

// ---------------- per-layer edge kernels ----------------
// k_gru: 3-section 48KB pack + 16KB tiles = 64KB LDS -> 2 blocks/CU (double
// the 80KB config's occupancy) and 96 (vs 128) MFMAs per 32-edge chunk.
// k_lstm: R13 plateau config (l=0 specialization reverted in R20: the
// epilogue, not the gate GEMM, dominates -- apply alone cost 99us vs 92.5).

__launch_bounds__(256, 1)
__global__ void k_gru(const int* __restrict__ src, const int* __restrict__ etype,
                      const u16* __restrict__ nfeat, const u16* __restrict__ equery,
                      const u16* __restrict__ efeat, const float* __restrict__ relw,
                      const u16* __restrict__ wpack,
                      const float* __restrict__ bx, const float* __restrict__ bh,
                      u16* __restrict__ msg) {
    __shared__ u16 sW[24576];
    __shared__ u16 sBuf[4][2048];
    const int tid = threadIdx.x;
    const int lane = tid & 63;
    const int wv = tid >> 6;
    {
        const uint4* gsrc = (const uint4*)wpack;
        uint4* ldst = (uint4*)sW;
        #pragma unroll
        for (int i = 0; i < 12; i++) ldst[tid + i * 256] = gsrc[tid + i * 256];
    }
    __syncthreads();

    const int row = lane & 15, kg = lane >> 4;
    u16* bufA = &sBuf[wv][0];
    u16* bufB = &sBuf[wv][1024];
    float br_[4], bz_[4], bxn_[4], bhn_[4];
    #pragma unroll
    for (int w = 0; w < 4; w++) {
        const int d = w * 16 + row;
        br_[w] = bx[d] + bh[d];
        bz_[w] = bx[64 + d] + bh[64 + d];
        bxn_[w] = bx[128 + d];
        bhn_[w] = bh[128 + d];
    }

    const int NCH = EN / 32;
    const int stride = gridDim.x * 4;
    int ch = blockIdx.x * 4 + wv;
    bf8_t pa0 = {}, pa1 = {}, pb0 = {}, pb1 = {};
    if (ch < NCH) {
        const int s0 = src[ch * 32 + row];
        const int s1 = src[ch * 32 + 16 + row];
        pa0 = *(const bf8_t*)(nfeat + (size_t)s0 * 64 + kg * 8);
        pa1 = *(const bf8_t*)(nfeat + (size_t)s0 * 64 + 32 + kg * 8);
        pb0 = *(const bf8_t*)(nfeat + (size_t)s1 * 64 + kg * 8);
        pb1 = *(const bf8_t*)(nfeat + (size_t)s1 * 64 + 32 + kg * 8);
    }

    for (; ch < NCH; ch += stride) {
        const int base = ch * 32;
        const int e0 = base + row;
        const int e1 = base + 16 + row;
        const int ty0 = etype[e0], ty1 = etype[e1];
        bf8_t af0[4], af1[4];
        {
            bf8_t q0 = *(const bf8_t*)(equery + (size_t)e0 * 64 + kg * 8);
            bf8_t q1 = *(const bf8_t*)(equery + (size_t)e0 * 64 + 32 + kg * 8);
            f4_t na, nb, qa, qb;
            unpk8(pa0, na, nb); unpk8(q0, qa, qb);
            af0[0] = pack8(na + qa, nb + qb);
            unpk8(pa1, na, nb); unpk8(q1, qa, qb);
            af0[1] = pack8(na + qa, nb + qb);
        }
        {
            bf8_t q0 = *(const bf8_t*)(equery + (size_t)e1 * 64 + kg * 8);
            bf8_t q1 = *(const bf8_t*)(equery + (size_t)e1 * 64 + 32 + kg * 8);
            f4_t na, nb, qa, qb;
            unpk8(pb0, na, nb); unpk8(q0, qa, qb);
            af1[0] = pack8(na + qa, nb + qb);
            unpk8(pb1, na, nb); unpk8(q1, qa, qb);
            af1[1] = pack8(na + qa, nb + qb);
        }
        {
            bf8_t x0 = *(const bf8_t*)(efeat + (size_t)e0 * 64 + kg * 8);
            bf8_t x1 = *(const bf8_t*)(efeat + (size_t)e0 * 64 + 32 + kg * 8);
            f4_t r0 = *(const f4_t*)(relw + ty0 * 64 + kg * 8);
            f4_t r1 = *(const f4_t*)(relw + ty0 * 64 + kg * 8 + 4);
            f4_t r2 = *(const f4_t*)(relw + ty0 * 64 + 32 + kg * 8);
            f4_t r3 = *(const f4_t*)(relw + ty0 * 64 + 32 + kg * 8 + 4);
            f4_t ea, eb;
            unpk8(x0, ea, eb);
            af0[2] = pack8(ea * r0, eb * r1);
            unpk8(x1, ea, eb);
            af0[3] = pack8(ea * r2, eb * r3);
        }
        {
            bf8_t x0 = *(const bf8_t*)(efeat + (size_t)e1 * 64 + kg * 8);
            bf8_t x1 = *(const bf8_t*)(efeat + (size_t)e1 * 64 + 32 + kg * 8);
            f4_t r0 = *(const f4_t*)(relw + ty1 * 64 + kg * 8);
            f4_t r1 = *(const f4_t*)(relw + ty1 * 64 + kg * 8 + 4);
            f4_t r2 = *(const f4_t*)(relw + ty1 * 64 + 32 + kg * 8);
            f4_t r3 = *(const f4_t*)(relw + ty1 * 64 + 32 + kg * 8 + 4);
            f4_t ea, eb;
            unpk8(x0, ea, eb);
            af1[2] = pack8(ea * r0, eb * r1);
            unpk8(x1, ea, eb);
            af1[3] = pack8(ea * r2, eb * r3);
        }
        // prefetch next chunk's nfeat gathers
        {
            const int nch = ch + stride;
            if (nch < NCH) {
                const int s0 = src[nch * 32 + row];
                const int s1 = src[nch * 32 + 16 + row];
                pa0 = *(const bf8_t*)(nfeat + (size_t)s0 * 64 + kg * 8);
                pa1 = *(const bf8_t*)(nfeat + (size_t)s0 * 64 + 32 + kg * 8);
                pb0 = *(const bf8_t*)(nfeat + (size_t)s1 * 64 + kg * 8);
                pb1 = *(const bf8_t*)(nfeat + (size_t)s1 * 64 + 32 + kg * 8);
            }
        }
        // stage h into the two wave tiles (swizzled b128 writes)
        *(bf8_t*)&bufA[tswz(row, kg * 8)] = af0[2];
        *(bf8_t*)&bufA[tswz(row, kg * 8 + 32)] = af0[3];
        *(bf8_t*)&bufB[tswz(row, kg * 8)] = af1[2];
        *(bf8_t*)&bufB[tswz(row, kg * 8 + 32)] = af1[3];

        #pragma unroll
        for (int w = 0; w < 4; w++) {
            facc_t ar0 = {0.f, 0.f, 0.f, 0.f}, az0 = ar0, axn0 = ar0, ahn0 = ar0;
            facc_t ar1 = ar0, az1 = ar0, axn1 = ar0, ahn1 = ar0;
            #pragma unroll
            for (int ks = 0; ks < 4; ks++) {
                const int rb = ((ks * 4 + w) * 3) * 512 + lane * 8;
                bf8_t b0 = *(const bf8_t*)&sW[rb];
                bf8_t b1 = *(const bf8_t*)&sW[rb + 512];
                bf8_t b2 = *(const bf8_t*)&sW[rb + 1024];
                ar0 = __builtin_amdgcn_mfma_f32_16x16x32_bf16(af0[ks], b0, ar0, 0, 0, 0);
                ar1 = __builtin_amdgcn_mfma_f32_16x16x32_bf16(af1[ks], b0, ar1, 0, 0, 0);
                az0 = __builtin_amdgcn_mfma_f32_16x16x32_bf16(af0[ks], b1, az0, 0, 0, 0);
                az1 = __builtin_amdgcn_mfma_f32_16x16x32_bf16(af1[ks], b1, az1, 0, 0, 0);
                if (ks < 2) {
                    axn0 = __builtin_amdgcn_mfma_f32_16x16x32_bf16(af0[ks], b2, axn0, 0, 0, 0);
                    axn1 = __builtin_amdgcn_mfma_f32_16x16x32_bf16(af1[ks], b2, axn1, 0, 0, 0);
                } else {
                    ahn0 = __builtin_amdgcn_mfma_f32_16x16x32_bf16(af0[ks], b2, ahn0, 0, 0, 0);
                    ahn1 = __builtin_amdgcn_mfma_f32_16x16x32_bf16(af1[ks], b2, ahn1, 0, 0, 0);
                }
            }
            #pragma unroll
            for (int rr = 0; rr < 4; rr++) {
                const int idx = tswz(kg * 4 + rr, w * 16 + row);
                {
                    const float r_ = sigm(ar0[rr] + br_[w]);
                    const float z_ = sigm(az0[rr] + bz_[w]);
                    const float n_ = tanh_f(axn0[rr] + bxn_[w] + r_ * (ahn0[rr] + bhn_[w]));
                    const float h_ = bf2f(bufA[idx]);
                    bufA[idx] = f2bf_hw((1.f - z_) * n_ + z_ * h_);
                }
                {
                    const float r_ = sigm(ar1[rr] + br_[w]);
                    const float z_ = sigm(az1[rr] + bz_[w]);
                    const float n_ = tanh_f(axn1[rr] + bxn_[w] + r_ * (ahn1[rr] + bhn_[w]));
                    const float h_ = bf2f(bufB[idx]);
                    bufB[idx] = f2bf_hw((1.f - z_) * n_ + z_ * h_);
                }
            }
        }
        // bulk store: four contiguous 1KB bursts
        const int r8 = lane >> 3, c8 = (lane & 7) * 8;
        bf8_t oA0 = *(const bf8_t*)&bufA[tswz(r8, c8)];
        bf8_t oA1 = *(const bf8_t*)&bufA[tswz(8 + r8, c8)];
        bf8_t oB0 = *(const bf8_t*)&bufB[tswz(r8, c8)];
        bf8_t oB1 = *(const bf8_t*)&bufB[tswz(8 + r8, c8)];
        *(bf8_t*)(msg + (size_t)base * 64 + r8 * 64 + c8) = oA0;
        *(bf8_t*)(msg + (size_t)base * 64 + (8 + r8) * 64 + c8) = oA1;
        *(bf8_t*)(msg + (size_t)(base + 16) * 64 + r8 * 64 + c8) = oB0;
        *(bf8_t*)(msg + (size_t)(base + 16) * 64 + (8 + r8) * 64 + c8) = oB1;
    }
}

__launch_bounds__(256, 1)
__global__ void k_lstm(const int* __restrict__ dst, const u16* __restrict__ nfeat_new,
                       const u16* __restrict__ wpack, const float* __restrict__ bb,
                       const float* __restrict__ g_ln, const float* __restrict__ b_ln,
                       u16* __restrict__ efeat, u16* __restrict__ equery) {
    __shared__ u16 sW[32768];
    __shared__ u16 sBuf[4][1024];
    const int tid = threadIdx.x;
    const int lane = tid & 63;
    const int wv = tid >> 6;
    {
        const uint4* gsrc = (const uint4*)wpack;
        uint4* ldst = (uint4*)sW;
        #pragma unroll
        for (int i = 0; i < 16; i++) ldst[tid + i * 256] = gsrc[tid + i * 256];
    }
    __syncthreads();

    const int row = lane & 15, kg = lane >> 4;
    u16* buf = &sBuf[wv][0];
    float lgv[4], lbv[4];
    #pragma unroll
    for (int w = 0; w < 4; w++) { lgv[w] = g_ln[w * 16 + row]; lbv[w] = b_ln[w * 16 + row]; }

    const int NCH = EN / 16;
    const int stride = gridDim.x * 4;
    int ch = blockIdx.x * 4 + wv;
    bf8_t pn0 = {}, pn1 = {}, pe0 = {}, pe1 = {};
    if (ch < NCH) {
        const int de = dst[ch * 16 + row];
        pn0 = *(const bf8_t*)(nfeat_new + (size_t)de * 64 + kg * 8);
        pn1 = *(const bf8_t*)(nfeat_new + (size_t)de * 64 + 32 + kg * 8);
        pe0 = *(const bf8_t*)(efeat + (size_t)(ch * 16 + row) * 64 + kg * 8);
        pe1 = *(const bf8_t*)(efeat + (size_t)(ch * 16 + row) * 64 + 32 + kg * 8);
    }

    for (; ch < NCH; ch += stride) {
        const int base = ch * 16;
        const int e = base + row;
        bf8_t af[4];
        af[0] = pn0;
        af[1] = pn1;
        af[2] = pe0;
        af[3] = pe1;
        // stage equery-old into the wave tile (swizzled)
        {
            bf8_t q0 = *(const bf8_t*)(equery + (size_t)e * 64 + kg * 8);
            bf8_t q1 = *(const bf8_t*)(equery + (size_t)e * 64 + 32 + kg * 8);
            *(bf8_t*)&buf[tswz(row, kg * 8)] = q0;
            *(bf8_t*)&buf[tswz(row, kg * 8 + 32)] = q1;
        }
        // prefetch next chunk's nfeat_new gather (hidden under the gate loop)
        {
            const int nch = ch + stride;
            if (nch < NCH) {
                const int de = dst[nch * 16 + row];
                pn0 = *(const bf8_t*)(nfeat_new + (size_t)de * 64 + kg * 8);
                pn1 = *(const bf8_t*)(nfeat_new + (size_t)de * 64 + 32 + kg * 8);
            }
        }

        // hc[w][rr] = packed (bf16 hh, bf16 cc); LN sums stay exact f32
        unsigned hc[4][4];
        float sh[4] = {0, 0, 0, 0}, sh2[4] = {0, 0, 0, 0};
        float sc[4] = {0, 0, 0, 0}, sc2[4] = {0, 0, 0, 0};

        #pragma unroll
        for (int w = 0; w < 4; w++) {
            facc_t ai = {0.f, 0.f, 0.f, 0.f}, afv = ai, ag = ai, ao = ai;
            #pragma unroll
            for (int ks = 0; ks < 4; ks++) {
                const int rb = (ks * 16 + w * 4) * 512 + lane * 8;
                bf8_t b0 = *(const bf8_t*)&sW[rb];
                bf8_t b1 = *(const bf8_t*)&sW[rb + 512];
                bf8_t b2 = *(const bf8_t*)&sW[rb + 1024];
                bf8_t b3 = *(const bf8_t*)&sW[rb + 1536];
                ai  = __builtin_amdgcn_mfma_f32_16x16x32_bf16(af[ks], b0, ai, 0, 0, 0);
                afv = __builtin_amdgcn_mfma_f32_16x16x32_bf16(af[ks], b1, afv, 0, 0, 0);
                ag  = __builtin_amdgcn_mfma_f32_16x16x32_bf16(af[ks], b2, ag, 0, 0, 0);
                ao  = __builtin_amdgcn_mfma_f32_16x16x32_bf16(af[ks], b3, ao, 0, 0, 0);
            }
            const int d = w * 16 + row;
            const float bi = bb[d], bf_ = bb[64 + d], bg = bb[128 + d], bo = bb[192 + d];
            #pragma unroll
            for (int rr = 0; rr < 4; rr++) {
                const int idx = tswz(kg * 4 + rr, d);
                const float eq = bf2f(buf[idx]);
                const float ci = sigm(ai[rr] + bi);
                const float cf = sigm(afv[rr] + bf_);
                const float cg = tanh_f(ag[rr] + bg);
                const float co = sigm(ao[rr] + bo);
                const float c_ = cf * eq + ci * cg;
                const float h_ = co * tanh_f(c_);
                hc[w][rr] = cvtpk(h_, c_);
                sh[rr] += h_; sh2[rr] += h_ * h_;
                sc[rr] += c_; sc2[rr] += c_ * c_;
            }
        }
        #pragma unroll
        for (int off = 1; off < 16; off <<= 1) {
            #pragma unroll
            for (int rr = 0; rr < 4; rr++) {
                sh[rr] += __shfl_xor(sh[rr], off, 64);
                sh2[rr] += __shfl_xor(sh2[rr], off, 64);
                sc[rr] += __shfl_xor(sc[rr], off, 64);
                sc2[rr] += __shfl_xor(sc2[rr], off, 64);
            }
        }
        float hm[4], hrs[4], cm[4], crs[4];
        #pragma unroll
        for (int rr = 0; rr < 4; rr++) {
            hm[rr] = sh[rr] * (1.f / 64.f);
            hrs[rr] = rsqrtf(sh2[rr] * (1.f / 64.f) - hm[rr] * hm[rr] + EPS_);
            cm[rr] = sc[rr] * (1.f / 64.f);
            crs[rr] = rsqrtf(sc2[rr] * (1.f / 64.f) - cm[rr] * cm[rr] + EPS_);
        }
        // prefetch next chunk's efeat rows (hidden under the two output passes)
        {
            const int nch = ch + stride;
            if (nch < NCH) {
                const size_t ne = (size_t)(nch * 16 + row) * 64;
                pe0 = *(const bf8_t*)(efeat + ne + kg * 8);
                pe1 = *(const bf8_t*)(efeat + ne + 32 + kg * 8);
            }
        }
        // pass 1: equery-new in place (cc = hi half of hc), bulk store
        #pragma unroll
        for (int w = 0; w < 4; w++) {
            #pragma unroll
            for (int rr = 0; rr < 4; rr++) {
                const int idx = tswz(kg * 4 + rr, w * 16 + row);
                const float eqo = bf2f(buf[idx]);
                const float c_ = bf2f((u16)(hc[w][rr] >> 16));
                buf[idx] = f2bf_hw(eqo + (c_ - cm[rr]) * crs[rr] * lgv[w] + lbv[w]);
            }
        }
        {
            const int r8 = lane >> 3, c8 = (lane & 7) * 8;
            bf8_t o0 = *(const bf8_t*)&buf[tswz(r8, c8)];
            bf8_t o1 = *(const bf8_t*)&buf[tswz(8 + r8, c8)];
            *(bf8_t*)(equery + (size_t)base * 64 + r8 * 64 + c8) = o0;
            *(bf8_t*)(equery + (size_t)base * 64 + (8 + r8) * 64 + c8) = o1;
        }
        // restage efeat-old (still in af[2..3])
        *(bf8_t*)&buf[tswz(row, kg * 8)] = af[2];
        *(bf8_t*)&buf[tswz(row, kg * 8 + 32)] = af[3];
        // pass 2: efeat-new in place (hh = lo half of hc), bulk store
        #pragma unroll
        for (int w = 0; w < 4; w++) {
            #pragma unroll
            for (int rr = 0; rr < 4; rr++) {
                const int idx = tswz(kg * 4 + rr, w * 16 + row);
                const float efo = bf2f(buf[idx]);
                const float h_ = bf2f((u16)(hc[w][rr] & 0xFFFFu));
                buf[idx] = f2bf_hw(efo + (h_ - hm[rr]) * hrs[rr] * lgv[w] + lbv[w]);
            }
        }
        {
            const int r8 = lane >> 3, c8 = (lane & 7) * 8;
            bf8_t o0 = *(const bf8_t*)&buf[tswz(r8, c8)];
            bf8_t o1 = *(const bf8_t*)&buf[tswz(8 + r8, c8)];
            *(bf8_t*)(efeat + (size_t)base * 64 + r8 * 64 + c8) = o0;
            *(bf8_t*)(efeat + (size_t)base * 64 + (8 + r8) * 64 + c8) = o1;
        }
    }
}

// k_node: unchanged structure (msg reads are wave-contiguous full lines).
__launch_bounds__(256)
__global__ void k_node(const int* __restrict__ row_ptr, const int* __restrict__ eid,
                       const u16* __restrict__ msg, const float* __restrict__ avg_sum,
                       const u16* __restrict__ wpack, const float* __restrict__ pb,
                       const float* __restrict__ g_ln, const float* __restrict__ b_ln,
                       u16* __restrict__ nfeat, u16* __restrict__ nfeat_new) {
    __shared__ u16 sAgg[16 * 280];
    __shared__ float sS[16], sT[16];
    __shared__ float sRed[4][16][2];
    const int lane = threadIdx.x & 63;
    const int w = threadIdx.x >> 6;
    const int base = blockIdx.x * 16;
    const float avg = avg_sum[0] * (1.f / (float)NN);

    bf8_t bw[8][3];
    #pragma unroll
    for (int ks = 0; ks < 8; ks++) {
        #pragma unroll
        for (int y = 0; y < 3; y++)
            bw[ks][y] = ((const bf8_t*)wpack)[((ks * 3 + y) * 4 + w) * 64 + lane];
    }

    float samp[4], satt[4];
    #pragma unroll
    for (int q = 0; q < 4; q++) {
        const int m = w * 4 + q;
        const int v = base + m;
        const int rs = row_ptr[v], re = row_ptr[v + 1];
        float s = 0.f, s2 = 0.f, mx = -INFINITY, mn = INFINITY;
        for (int i = rs; i < re; i++) {
            const int e = eid[i];
            const float mv = bf2f(msg[(size_t)e * 64 + lane]);
            s += mv; s2 += mv * mv; mx = fmaxf(mx, mv); mn = fminf(mn, mv);
        }
        const float deg = (float)(re - rs);
        const float dsafe = fmaxf(deg, 1.f);
        const float mean = s / dsafe;
        const float sq = s2 / dsafe;
        const bool has = (re - rs) > 0;
        const float amx = has ? mx : 0.f;
        const float amn = has ? mn : 0.f;
        const float astd = sqrtf(fmaxf(sq - mean * mean, 0.f) + EPS_);
        uint2 pk;
        pk.x = cvtpk(mean, amx);
        pk.y = cvtpk(amn, astd);
        *(uint2*)&sAgg[m * 280 + lane * 4] = pk;
        const float ld = logf(deg + 1.f);
        samp[q] = ld / avg;
        satt[q] = ld > 0.f ? avg / fmaxf(ld, EPS_) : 0.f;
    }
    if (lane == 0) {
        #pragma unroll
        for (int q = 0; q < 4; q++) { sS[w * 4 + q] = samp[q]; sT[w * 4 + q] = satt[q]; }
    }
    __syncthreads();

    facc_t c0 = {0.f, 0.f, 0.f, 0.f}, c1 = c0, c2 = c0;
    const int arow = lane & 15, acol = (lane >> 4) * 8;
    #pragma unroll
    for (int ks = 0; ks < 8; ks++) {
        bf8_t af = *(const bf8_t*)&sAgg[arow * 280 + ks * 32 + acol];
        c0 = __builtin_amdgcn_mfma_f32_16x16x32_bf16(af, bw[ks][0], c0, 0, 0, 0);
        c1 = __builtin_amdgcn_mfma_f32_16x16x32_bf16(af, bw[ks][1], c1, 0, 0, 0);
        c2 = __builtin_amdgcn_mfma_f32_16x16x32_bf16(af, bw[ks][2], c2, 0, 0, 0);
    }

    const int d = w * 16 + (lane & 15);
    const float pbl = pb[d], lg = g_ln[d], lb = b_ln[d];
    float nf[4];
    #pragma unroll
    for (int rr = 0; rr < 4; rr++) {
        const int m = (lane >> 4) * 4 + rr;
        nf[rr] = pbl + c0[rr] + sS[m] * c1[rr] + sT[m] * c2[rr];
        nfeat_new[(size_t)(base + m) * 64 + d] = f2bf_hw(nf[rr]);
    }
    float ps[4], ps2[4];
    #pragma unroll
    for (int rr = 0; rr < 4; rr++) { ps[rr] = nf[rr]; ps2[rr] = nf[rr] * nf[rr]; }
    #pragma unroll
    for (int off = 1; off < 16; off <<= 1) {
        #pragma unroll
        for (int rr = 0; rr < 4; rr++) {
            ps[rr] += __shfl_xor(ps[rr], off, 64);
            ps2[rr] += __shfl_xor(ps2[rr], off, 64);
        }
    }
    if ((lane & 15) == 0) {
        #pragma unroll
        for (int rr = 0; rr < 4; rr++) {
            const int m = (lane >> 4) * 4 + rr;
            sRed[w][m][0] = ps[rr];
            sRed[w][m][1] = ps2[rr];
        }
    }
    __syncthreads();
    #pragma unroll
    for (int rr = 0; rr < 4; rr++) {
        const int m = (lane >> 4) * 4 + rr;
        float ts = 0.f, ts2 = 0.f;
        #pragma unroll
        for (int w2 = 0; w2 < 4; w2++) { ts += sRed[w2][m][0]; ts2 += sRed[w2][m][1]; }
        const float mean = ts * (1.f / 64.f);
        const float var = ts2 * (1.f / 64.f) - mean * mean;
        const size_t off = (size_t)(base + m) * 64 + d;
        nfeat[off] = f2bf_hw(bf2f(nfeat[off]) + (nf[rr] - mean) * rsqrtf(var + EPS_) * lg + lb);
    }
}

__global__ void k_snap(const int* __restrict__ tgt, const int* __restrict__ src,
                       const u16* __restrict__ efeat, const u16* __restrict__ equery,
                       const u16* __restrict__ nfeat,
                       float* jk_e, float* jk_q, float* jk_n) {
    int t = blockIdx.x, d = threadIdx.x;
    int e = tgt[t];
    jk_e[t * 64 + d] = bf2f(efeat[(size_t)e * 64 + d]);
    jk_q[t * 64 + d] = bf2f(equery[(size_t)e * 64 + d]);
    int v = src[e];
    jk_n[t * 64 + d] = bf2f(nfeat[v * 64 + d]);
}

// ---------------- output head ----------------

__global__ void k_jk(const float* __restrict__ jk_e, const float* __restrict__ jk_q, const float* __restrict__ jk_n,
                     const float* __restrict__ ejk_w, const float* __restrict__ ejk_b,
                     const float* __restrict__ qjk_w, const float* __restrict__ qjk_b,
                     const float* __restrict__ njk_w, const float* __restrict__ njk_b,
                     float* ejk_o, float* qjk_o, float* njk_o) {
    int t = blockIdx.x, d = threadIdx.x;
    float ae = ejk_b[d], aq = qjk_b[d], an_ = njk_b[d];
    for (int l = 0; l < 3; l++) {
        for (int dd = 0; dd < 64; dd++) {
            int k = l * 64 + dd;
            ae += jk_e[(l * 64 + t) * 64 + dd] * ejk_w[k * 64 + d];
            aq += jk_q[(l * 64 + t) * 64 + dd] * qjk_w[k * 64 + d];
            an_ += jk_n[(l * 64 + t) * 64 + dd] * njk_w[k * 64 + d];
        }
    }
    ejk_o[t * 64 + d] = ae;
    qjk_o[t * 64 + d] = aq;
    njk_o[t * 64 + d] = an_;
}

__global__ void k_final(const float* __restrict__ ejk_o, const float* __restrict__ qjk_o,
                        const float* __restrict__ njk_o,
                        const float* __restrict__ fc_w, const float* __restrict__ fc_b,
                        float* out) {
    int b = blockIdx.x, d = threadIdx.x;
    int t0 = 2 * b, t1 = 2 * b + 1;
    float r = ejk_o[t0 * 64 + d] * fc_w[d] + qjk_o[t0 * 64 + d] * fc_w[64 + d]
            + njk_o[t0 * 64 + d] * fc_w[128 + d] + njk_o[t1 * 64 + d] * fc_w[192 + d];
    float lf = ejk_o[t1 * 64 + d] * fc_w[d] + qjk_o[t1 * 64 + d] * fc_w[64 + d]
             + njk_o[t1 * 64 + d] * fc_w[128 + d] + njk_o[t0 * 64 + d] * fc_w[192 + d];
    #pragma unroll
    for (int off = 32; off > 0; off >>= 1) { r += __shfl_xor(r, off, 64); lf += __shfl_xor(lf, off, 64); }
    if (d == 0) out[b] = fmaxf(r + fc_b[0], lf + fc_b[0]);
}

// ---------------- host launcher ----------------

extern "C" void kernel_launch(void* const* d_in, const int* in_sizes, int n_in,
                              void* d_out, int out_size, void* d_ws, size_t ws_size,
                              hipStream_t stream) {
    const int* src   = (const int*)d_in[0];
    const int* dst   = (const int*)d_in[1];
    const int* etype = (const int*)d_in[2];
    const int* egid  = (const int*)d_in[3];
    const int* tgt   = (const int*)d_in[4];
    const float* query_emb = (const float*)d_in[6];
    const float* eqp_w = (const float*)d_in[7];
    const float* eqp_b = (const float*)d_in[8];
    const float* rel_w = (const float*)d_in[9];
    const float* gru_wx = (const float*)d_in[10];
    const float* gru_wh = (const float*)d_in[11];
    const float* gru_bx = (const float*)d_in[12];
    const float* gru_bh = (const float*)d_in[13];
    const float* pna_w = (const float*)d_in[14];
    const float* pna_b = (const float*)d_in[15];
    const float* lstm_wx = (const float*)d_in[16];
    const float* lstm_wh = (const float*)d_in[17];
    const float* lstm_b = (const float*)d_in[18];
    const float* ln_g = (const float*)d_in[19];
    const float* ln_b = (const float*)d_in[20];
    const float* ejk_w = (const float*)d_in[21];
    const float* ejk_b = (const float*)d_in[22];
    const float* njk_w = (const float*)d_in[23];
    const float* njk_b = (const float*)d_in[24];
    const float* qjk_w = (const float*)d_in[25];
    const float* qjk_b = (const float*)d_in[26];
    const float* fc_w = (const float*)d_in[27];
    const float* fc_b = (const float*)d_in[28];

    u16* q16 = (u16*)d_ws;
    u16* equery = q16;     q16 += (size_t)EN * 64;
    u16* efeat = q16;      q16 += (size_t)EN * 64;
    u16* msg = q16;        q16 += (size_t)EN * 64;
    u16* nfeat = q16;      q16 += (size_t)NN * 64;
    u16* nfeat_new = q16;  q16 += (size_t)NN * 64;
    u16* wpg = q16;        q16 += 3 * 24576;
    u16* wpl = q16;        q16 += 3 * 32768;
    u16* wpp = q16;        q16 += 3 * 49152;
    u16* msg_row = q16;    q16 += 32 * 64;
    q16 += 32;  // alignment pad
    float* p = (float*)q16;
    float* tgt_q = p;     p += 64 * 64;
    float* eq_g = p;      p += 32 * 64;
    float* jk_e = p;      p += 3 * 64 * 64;
    float* jk_q = p;      p += 3 * 64 * 64;
    float* jk_n = p;      p += 3 * 64 * 64;
    float* ejk_o = p;     p += 64 * 64;
    float* qjk_o = p;     p += 64 * 64;
    float* njk_o = p;     p += 64 * 64;
    float* avg_sum = p;   p += 64;
    int* ip = (int*)p;
    int* row_ptr = ip; ip += NN + 1;
    int* fillp = ip;   ip += NN;
    int* cnt = ip;     ip += NN;
    int* outcnt = ip;  ip += NN;
    int* eid = ip;     ip += EN;
    int* bsum = ip;    ip += 64;
    int* boff = ip;    ip += 64;
    if ((size_t)((char*)ip - (char*)d_ws) > ws_size) return;

    k_init<<<4096, 256, 0, stream>>>(efeat, nfeat, cnt, outcnt, avg_sum);
    k_count<<<1024, 256, 0, stream>>>(src, dst, cnt, outcnt);
    k_scan1<<<40, 1024, 0, stream>>>(cnt, row_ptr, bsum);
    k_scan2<<<1, 64, 0, stream>>>(bsum, boff, row_ptr);
    k_scan3<<<40, 1024, 0, stream>>>(row_ptr, fillp, boff);
    k_fill<<<1024, 256, 0, stream>>>(dst, fillp, eid);
    k_avg<<<(NN + 255) / 256, 256, 0, stream>>>(outcnt, avg_sum);
    k_tgt<<<64, 64, 0, stream>>>(tgt, etype, query_emb, tgt_q, efeat);
    k_eqg<<<32, 64, 0, stream>>>(tgt_q, eqp_w, eqp_b, eq_g);
    k_equery<<<8192, 256, 0, stream>>>(egid, eq_g, equery);
    k_pack_gru<<<dim3(16, 3), 256, 0, stream>>>(gru_wx, gru_wh, wpg);
    k_pack_lstm<<<dim3(16, 3), 256, 0, stream>>>(lstm_wx, lstm_wh, wpl);
    k_pack_pna<<<dim3(24, 3), 256, 0, stream>>>(pna_w, wpp);

    for (int l = 0; l < 3; l++) {
        if (l == 0) {
            k_gru0_rows<<<32, 64, 0, stream>>>(eq_g, gru_wx, gru_bx, gru_bh, msg_row);
            k_gru0_scatter<<<4096, 256, 0, stream>>>(egid, msg_row, msg);
            k_gru0_fix<<<64, 64, 0, stream>>>(tgt, etype, equery, efeat, rel_w,
                gru_wx, gru_wh, gru_bx, gru_bh, msg);
        } else {
            k_gru<<<512, 256, 0, stream>>>(src, etype, nfeat, equery, efeat,
                rel_w + (size_t)l * NR * 64, wpg + (size_t)l * 24576,
                gru_bx + (size_t)l * 192, gru_bh + (size_t)l * 192, msg);
        }
        k_node<<<NN / 16, 256, 0, stream>>>(row_ptr, eid, msg, avg_sum,
            wpp + (size_t)l * 49152, pna_b + (size_t)l * 64,
            ln_g + (size_t)l * 64, ln_b + (size_t)l * 64, nfeat, nfeat_new);
        k_lstm<<<512, 256, 0, stream>>>(dst, nfeat_new, wpl + (size_t)l * 32768,
            lstm_b + (size_t)l * 256,
            ln_g + (size_t)l * 64, ln_b + (size_t)l * 64, efeat, equery);
        k_snap<<<64, 64, 0, stream>>>(tgt, src, efeat, equery, nfeat,
            jk_e + l * 4096, jk_q + l * 4096, jk_n + l * 4096);
    }

    k_jk<<<64, 64, 0, stream>>>(jk_e, jk_q, jk_n, ejk_w, ejk_b, qjk_w, qjk_b, njk_w, njk_b,
                                ejk_o, qjk_o, njk_o);
    k_final<<<32, 64, 0, stream>>>(ejk_o, qjk_o, njk_o, fc_w, fc_b, (float*)d_out);
}

// Round 21
// 678.765 us; speedup vs baseline: 1.1305x; 1.1000x over previous
//
#include <hip/hip_runtime.h>
#include <math.h>

#define EN 256000
#define NN 40000
#define NR 474
#define EPS_ 1e-5f

typedef unsigned short u16;
typedef __attribute__((ext_vector_type(4))) float f4_t;
typedef __attribute__((ext_vector_type(8))) short bf8_t;
typedef __attribute__((ext_vector_type(4))) float facc_t;

__device__ __forceinline__ float sigm(float x) { return 1.f / (1.f + __expf(-x)); }
__device__ __forceinline__ float tanh_f(float x) { float e = __expf(2.f * x); return 1.f - 2.f / (e + 1.f); }

__device__ __forceinline__ u16 f2bf(float f) {
    unsigned u = __float_as_uint(f);
    return (u16)((u + 0x7FFFu + ((u >> 16) & 1u)) >> 16);
}
__device__ __forceinline__ unsigned cvtpk(float lo, float hi) {
    unsigned r;
    asm("v_cvt_pk_bf16_f32 %0, %1, %2" : "=v"(r) : "v"(lo), "v"(hi));
    return r;
}
__device__ __forceinline__ u16 f2bf_hw(float v) { return (u16)cvtpk(v, v); }
__device__ __forceinline__ float bf2f(u16 u) { return __uint_as_float(((unsigned)u) << 16); }

__device__ __forceinline__ bf8_t pack8(f4_t a, f4_t b) {
    union { unsigned u[4]; bf8_t v; } r;
    r.u[0] = cvtpk(a[0], a[1]);
    r.u[1] = cvtpk(a[2], a[3]);
    r.u[2] = cvtpk(b[0], b[1]);
    r.u[3] = cvtpk(b[2], b[3]);
    return r.v;
}
__device__ __forceinline__ void unpk8(bf8_t v, f4_t& a, f4_t& b) {
    a[0] = bf2f((u16)v[0]); a[1] = bf2f((u16)v[1]); a[2] = bf2f((u16)v[2]); a[3] = bf2f((u16)v[3]);
    b[0] = bf2f((u16)v[4]); b[1] = bf2f((u16)v[5]); b[2] = bf2f((u16)v[6]); b[3] = bf2f((u16)v[7]);
}

// swizzled u16 index into a 16x64 wave tile (see round-11 analysis)
__device__ __forceinline__ int tswz(int r, int u) {
    return r * 64 + (u ^ (((r >> 2) & 3) << 4));
}

// ---------------- init / graph prep ----------------

__global__ void k_init(u16* efeat, u16* nfeat, int* cnt, int* outcnt, float* avg_sum) {
    long total = (long)EN * 32;
    unsigned* ef = (unsigned*)efeat;
    unsigned* nf = (unsigned*)nfeat;
    for (long i = blockIdx.x * (long)blockDim.x + threadIdx.x; i < total; i += (long)gridDim.x * blockDim.x) {
        ef[i] = 0u;
        if (i < (long)NN * 32) nf[i] = 0u;
        if (i < NN) { cnt[i] = 0; outcnt[i] = 0; }
        if (i == 0) avg_sum[0] = 0.f;
    }
}

__global__ void k_count(const int* __restrict__ src, const int* __restrict__ dst, int* cnt, int* outcnt) {
    for (int e = blockIdx.x * blockDim.x + threadIdx.x; e < EN; e += gridDim.x * blockDim.x) {
        atomicAdd(&cnt[dst[e]], 1);
        atomicAdd(&outcnt[src[e]], 1);
    }
}

// 3-kernel device-wide exclusive scan
__global__ void k_scan1(const int* __restrict__ cnt, int* __restrict__ row_ptr, int* __restrict__ bsum) {
    __shared__ int tmp[1024];
    const int b = blockIdx.x, t = threadIdx.x;
    const int idx = b * 1024 + t;
    const int v = (idx < NN) ? cnt[idx] : 0;
    tmp[t] = v;
    __syncthreads();
    for (int off = 1; off < 1024; off <<= 1) {
        int u = (t >= off) ? tmp[t - off] : 0;
        __syncthreads();
        tmp[t] += u;
        __syncthreads();
    }
    if (idx < NN) row_ptr[idx] = tmp[t] - v;
    if (t == 1023) bsum[b] = tmp[t];
}

__global__ void k_scan2(const int* __restrict__ bsum, int* __restrict__ boff, int* __restrict__ row_ptr) {
    const int t = threadIdx.x;
    const int v = (t < 40) ? bsum[t] : 0;
    int s = v;
    #pragma unroll
    for (int off = 1; off < 64; off <<= 1) {
        int u = __shfl_up(s, off, 64);
        if (t >= off) s += u;
    }
    if (t < 40) boff[t] = s - v;
    if (t == 63) row_ptr[NN] = s;
}

__global__ void k_scan3(int* __restrict__ row_ptr, int* __restrict__ fillp, const int* __restrict__ boff) {
    const int idx = blockIdx.x * 1024 + threadIdx.x;
    if (idx < NN) {
        const int r = row_ptr[idx] + boff[blockIdx.x];
        row_ptr[idx] = r;
        fillp[idx] = r;
    }
}

// CSR permutation: pos = inv[e]; all per-edge feature arrays live in dst-sorted
// order. Also emits coalescable per-position copies of src/dst/etype/egid.
__global__ void k_fill(const int* __restrict__ src, const int* __restrict__ dst,
                       const int* __restrict__ etype, const int* __restrict__ egid,
                       int* fillp, int* __restrict__ inv,
                       int* __restrict__ src_s, int* __restrict__ dst_s,
                       int* __restrict__ ty_s, int* __restrict__ gid_s) {
    for (int e = blockIdx.x * blockDim.x + threadIdx.x; e < EN; e += gridDim.x * blockDim.x) {
        const int de = dst[e];
        const int pos = atomicAdd(&fillp[de], 1);
        inv[e] = pos;
        src_s[pos] = src[e];
        dst_s[pos] = de;
        ty_s[pos] = etype[e];
        gid_s[pos] = egid[e];
    }
}

__global__ void k_avg(const int* __restrict__ outcnt, float* __restrict__ avg_sum) {
    int n = blockIdx.x * blockDim.x + threadIdx.x;
    float v = 0.f;
    if (n < NN) v = logf((float)outcnt[n] + 1.f);
    #pragma unroll
    for (int off = 32; off > 0; off >>= 1) v += __shfl_xor(v, off, 64);
    if ((threadIdx.x & 63) == 0) atomicAdd(avg_sum, v);
}

__global__ void k_tgt(const int* __restrict__ tgt, const int* __restrict__ etype,
                      const int* __restrict__ inv,
                      const float* __restrict__ query_emb, float* tgt_q, u16* efeat) {
    int t = blockIdx.x, d = threadIdx.x;
    int e = tgt[t];
    int r = etype[e];
    float v = query_emb[r * 64 + d];
    tgt_q[t * 64 + d] = v;
    efeat[(size_t)inv[e] * 64 + d] = f2bf(v);
}

__global__ void k_eqg(const float* __restrict__ tgt_q, const float* __restrict__ eqp_w,
                      const float* __restrict__ eqp_b, float* eq_g) {
    int g = blockIdx.x, d = threadIdx.x;
    float acc = eqp_b[d];
    for (int k = 0; k < 128; k++) {
        float a = tgt_q[(2 * g + (k >> 6)) * 64 + (k & 63)];
        acc += a * eqp_w[k * 64 + d];
    }
    eq_g[g * 64 + d] = acc;
}

__global__ void k_equery(const int* __restrict__ gid_s, const float* __restrict__ eq_g, u16* equery) {
    long total = (long)EN * 64;
    for (long i = blockIdx.x * (long)blockDim.x + threadIdx.x; i < total; i += (long)gridDim.x * blockDim.x) {
        int e = (int)(i >> 6), d = (int)(i & 63);
        equery[i] = f2bf(eq_g[gid_s[e] * 64 + d]);
    }
}

// ---------------- layer-0 GRU specialization (sorted order) ----------------

__global__ void k_gru0_rows(const float* __restrict__ eq_g, const float* __restrict__ wx,
                            const float* __restrict__ bx, const float* __restrict__ bh,
                            u16* __restrict__ msg_row) {
    const int g = blockIdx.x, d = threadIdx.x;  // 32 x 64
    float ar = bx[d], az = bx[64 + d], an = bx[128 + d];
    for (int k = 0; k < 64; k++) {
        const float x = bf2f(f2bf(eq_g[g * 64 + k]));
        ar += x * wx[k * 192 + d];
        az += x * wx[k * 192 + 64 + d];
        an += x * wx[k * 192 + 128 + d];
    }
    const float r = sigm(ar + bh[d]);
    const float z = sigm(az + bh[64 + d]);
    const float n = tanh_f(an + r * bh[128 + d]);
    msg_row[g * 64 + d] = f2bf((1.f - z) * n);
}

__global__ void k_gru0_scatter(const int* __restrict__ gid_s, const u16* __restrict__ msg_row,
                               u16* __restrict__ msg) {
    long total = (long)EN * 32;
    const unsigned* mr = (const unsigned*)msg_row;
    unsigned* m = (unsigned*)msg;
    for (long i = blockIdx.x * (long)blockDim.x + threadIdx.x; i < total; i += (long)gridDim.x * blockDim.x) {
        const int e = (int)(i >> 5);
        const int dd = (int)(i & 31);
        m[i] = mr[gid_s[e] * 32 + dd];
    }
}

__global__ void k_gru0_fix(const int* __restrict__ tgt, const int* __restrict__ etype,
                           const int* __restrict__ inv,
                           const u16* __restrict__ equery, const u16* __restrict__ efeat,
                           const float* __restrict__ relw,
                           const float* __restrict__ wx, const float* __restrict__ wh,
                           const float* __restrict__ bx, const float* __restrict__ bh,
                           u16* __restrict__ msg) {
    const int t = blockIdx.x, d = threadIdx.x;  // 64 x 64
    const int e = tgt[t];
    const int pos = inv[e];
    const int ty = etype[e];
    float ar = bx[d], az = bx[64 + d], an = bx[128 + d];
    float br = bh[d], bz = bh[64 + d], bn = bh[128 + d];
    for (int k = 0; k < 64; k++) {
        const float x = bf2f(equery[(size_t)pos * 64 + k]);
        const float h = bf2f(efeat[(size_t)pos * 64 + k]) * relw[ty * 64 + k];
        ar += x * wx[k * 192 + d];       br += h * wh[k * 192 + d];
        az += x * wx[k * 192 + 64 + d];  bz += h * wh[k * 192 + 64 + d];
        an += x * wx[k * 192 + 128 + d]; bn += h * wh[k * 192 + 128 + d];
    }
    const float r = sigm(ar + br);
    const float z = sigm(az + bz);
    const float n = tanh_f(an + r * bn);
    const float h_ = bf2f(efeat[(size_t)pos * 64 + d]) * relw[ty * 64 + d];
    msg[(size_t)pos * 64 + d] = f2bf_hw((1.f - z) * n + z * h_);
}

// ---------------- weight packing for MFMA ----------------
// GRU pack, 3 sections (r, z, n): n is Wx_n for k<64, Wh_n for k>=64.

__global__ void k_pack_gru(const float* __restrict__ wx, const float* __restrict__ wh,
                           u16* __restrict__ out) {
    int l = blockIdx.y;
    wx += (size_t)l * 64 * 192; wh += (size_t)l * 64 * 192; out += (size_t)l * 24576;
    for (int idx = blockIdx.x * blockDim.x + threadIdx.x; idx < 24576; idx += gridDim.x * blockDim.x) {
        int rec = idx >> 3, j = idx & 7;
        int lane = rec & 63, rw = rec >> 6;
        int g = rw % 3, ksw = rw / 3;
        int w = ksw & 3, ks = ksw >> 2;
        int k = ks * 32 + (lane >> 4) * 8 + j;
        int d = w * 16 + (lane & 15);
        float v;
        if (g == 0)      v = k < 64 ? wx[k * 192 + d]       : wh[(k - 64) * 192 + d];
        else if (g == 1) v = k < 64 ? wx[k * 192 + 64 + d]  : wh[(k - 64) * 192 + 64 + d];
        else             v = k < 64 ? wx[k * 192 + 128 + d] : wh[(k - 64) * 192 + 128 + d];
        out[idx] = f2bf(v);
    }
}

__global__ void k_pack_lstm(const float* __restrict__ wx, const float* __restrict__ wh,
                            u16* __restrict__ out) {
    int l = blockIdx.y;
    wx += (size_t)l * 64 * 256; wh += (size_t)l * 64 * 256; out += (size_t)l * 32768;
    for (int idx = blockIdx.x * blockDim.x + threadIdx.x; idx < 32768; idx += gridDim.x * blockDim.x) {
        int rec = idx >> 3, j = idx & 7;
        int lane = rec & 63, ksnt = rec >> 6;
        int nt = ksnt & 15, ks = ksnt >> 4;
        int k = ks * 32 + (lane >> 4) * 8 + j;
        int g = nt & 3, d = (nt >> 2) * 16 + (lane & 15);
        float v = k < 64 ? wx[k * 256 + g * 64 + d] : wh[(k - 64) * 256 + g * 64 + d];
        out[idx] = f2bf(v);
    }
}

__global__ void k_pack_pna(const float* __restrict__ pw, u16* __restrict__ out) {
    int l = blockIdx.y;
    pw += (size_t)l * 768 * 64; out += (size_t)l * 49152;
    for (int idx = blockIdx.x * blockDim.x + threadIdx.x; idx < 49152; idx += gridDim.x * blockDim.x) {
        int rec = idx >> 3, j = idx & 7;
        int lane = rec & 63, f = rec >> 6;
        int w = f & 3, ys = f >> 2;
        int y = ys % 3, ks = ys / 3;
        int k = ks * 32 + (lane >> 4) * 8 + j;
        int sec = k & 3, dfeat = k >> 2;
        int d = w * 16 + (lane & 15);
        out[idx] = f2bf(pw[(size_t)(y * 256 + sec * 64 + dfeat) * 64 + d]);
    }
}

// ---------------- per-layer edge kernels (CSR-sorted edge order) ----------------

__launch_bounds__(256, 1)
__global__ void k_gru(const int* __restrict__ src_s, const int* __restrict__ ty_s,
                      const u16* __restrict__ nfeat, const u16* __restrict__ equery,
                      const u16* __restrict__ efeat, const float* __restrict__ relw,
                      const u16* __restrict__ wpack,
                      const float* __restrict__ bx, const float* __restrict__ bh,
                      u16* __restrict__ msg) {
    __shared__ u16 sW[24576];
    __shared__ u16 sBuf[4][2048];
    const int tid = threadIdx.x;
    const int lane = tid & 63;
    const int wv = tid >> 6;
    {
        const uint4* gsrc = (const uint4*)wpack;
        uint4* ldst = (uint4*)sW;
        #pragma unroll
        for (int i = 0; i < 12; i++) ldst[tid + i * 256] = gsrc[tid + i * 256];
    }
    __syncthreads();

    const int row = lane & 15, kg = lane >> 4;
    u16* bufA = &sBuf[wv][0];
    u16* bufB = &sBuf[wv][1024];
    float br_[4], bz_[4], bxn_[4], bhn_[4];
    #pragma unroll
    for (int w = 0; w < 4; w++) {
        const int d = w * 16 + row;
        br_[w] = bx[d] + bh[d];
        bz_[w] = bx[64 + d] + bh[64 + d];
        bxn_[w] = bx[128 + d];
        bhn_[w] = bh[128 + d];
    }

    const int NCH = EN / 32;
    const int stride = gridDim.x * 4;
    int ch = blockIdx.x * 4 + wv;
    bf8_t pa0 = {}, pa1 = {}, pb0 = {}, pb1 = {};
    if (ch < NCH) {
        const int s0 = src_s[ch * 32 + row];
        const int s1 = src_s[ch * 32 + 16 + row];
        pa0 = *(const bf8_t*)(nfeat + (size_t)s0 * 64 + kg * 8);
        pa1 = *(const bf8_t*)(nfeat + (size_t)s0 * 64 + 32 + kg * 8);
        pb0 = *(const bf8_t*)(nfeat + (size_t)s1 * 64 + kg * 8);
        pb1 = *(const bf8_t*)(nfeat + (size_t)s1 * 64 + 32 + kg * 8);
    }

    for (; ch < NCH; ch += stride) {
        const int base = ch * 32;
        const int e0 = base + row;
        const int e1 = base + 16 + row;
        const int ty0 = ty_s[e0], ty1 = ty_s[e1];
        bf8_t af0[4], af1[4];
        {
            bf8_t q0 = *(const bf8_t*)(equery + (size_t)e0 * 64 + kg * 8);
            bf8_t q1 = *(const bf8_t*)(equery + (size_t)e0 * 64 + 32 + kg * 8);
            f4_t na, nb, qa, qb;
            unpk8(pa0, na, nb); unpk8(q0, qa, qb);
            af0[0] = pack8(na + qa, nb + qb);
            unpk8(pa1, na, nb); unpk8(q1, qa, qb);
            af0[1] = pack8(na + qa, nb + qb);
        }
        {
            bf8_t q0 = *(const bf8_t*)(equery + (size_t)e1 * 64 + kg * 8);
            bf8_t q1 = *(const bf8_t*)(equery + (size_t)e1 * 64 + 32 + kg * 8);
            f4_t na, nb, qa, qb;
            unpk8(pb0, na, nb); unpk8(q0, qa, qb);
            af1[0] = pack8(na + qa, nb + qb);
            unpk8(pb1, na, nb); unpk8(q1, qa, qb);
            af1[1] = pack8(na + qa, nb + qb);
        }
        {
            bf8_t x0 = *(const bf8_t*)(efeat + (size_t)e0 * 64 + kg * 8);
            bf8_t x1 = *(const bf8_t*)(efeat + (size_t)e0 * 64 + 32 + kg * 8);
            f4_t r0 = *(const f4_t*)(relw + ty0 * 64 + kg * 8);
            f4_t r1 = *(const f4_t*)(relw + ty0 * 64 + kg * 8 + 4);
            f4_t r2 = *(const f4_t*)(relw + ty0 * 64 + 32 + kg * 8);
            f4_t r3 = *(const f4_t*)(relw + ty0 * 64 + 32 + kg * 8 + 4);
            f4_t ea, eb;
            unpk8(x0, ea, eb);
            af0[2] = pack8(ea * r0, eb * r1);
            unpk8(x1, ea, eb);
            af0[3] = pack8(ea * r2, eb * r3);
        }
        {
            bf8_t x0 = *(const bf8_t*)(efeat + (size_t)e1 * 64 + kg * 8);
            bf8_t x1 = *(const bf8_t*)(efeat + (size_t)e1 * 64 + 32 + kg * 8);
            f4_t r0 = *(const f4_t*)(relw + ty1 * 64 + kg * 8);
            f4_t r1 = *(const f4_t*)(relw + ty1 * 64 + kg * 8 + 4);
            f4_t r2 = *(const f4_t*)(relw + ty1 * 64 + 32 + kg * 8);
            f4_t r3 = *(const f4_t*)(relw + ty1 * 64 + 32 + kg * 8 + 4);
            f4_t ea, eb;
            unpk8(x0, ea, eb);
            af1[2] = pack8(ea * r0, eb * r1);
            unpk8(x1, ea, eb);
            af1[3] = pack8(ea * r2, eb * r3);
        }
        // prefetch next chunk's nfeat gathers
        {
            const int nch = ch + stride;
            if (nch < NCH) {
                const int s0 = src_s[nch * 32 + row];
                const int s1 = src_s[nch * 32 + 16 + row];
                pa0 = *(const bf8_t*)(nfeat + (size_t)s0 * 64 + kg * 8);
                pa1 = *(const bf8_t*)(nfeat + (size_t)s0 * 64 + 32 + kg * 8);
                pb0 = *(const bf8_t*)(nfeat + (size_t)s1 * 64 + kg * 8);
                pb1 = *(const bf8_t*)(nfeat + (size_t)s1 * 64 + 32 + kg * 8);
            }
        }
        // stage h into the two wave tiles (swizzled b128 writes)
        *(bf8_t*)&bufA[tswz(row, kg * 8)] = af0[2];
        *(bf8_t*)&bufA[tswz(row, kg * 8 + 32)] = af0[3];
        *(bf8_t*)&bufB[tswz(row, kg * 8)] = af1[2];
        *(bf8_t*)&bufB[tswz(row, kg * 8 + 32)] = af1[3];

        #pragma unroll
        for (int w = 0; w < 4; w++) {
            facc_t ar0 = {0.f, 0.f, 0.f, 0.f}, az0 = ar0, axn0 = ar0, ahn0 = ar0;
            facc_t ar1 = ar0, az1 = ar0, axn1 = ar0, ahn1 = ar0;
            #pragma unroll
            for (int ks = 0; ks < 4; ks++) {
                const int rb = ((ks * 4 + w) * 3) * 512 + lane * 8;
                bf8_t b0 = *(const bf8_t*)&sW[rb];
                bf8_t b1 = *(const bf8_t*)&sW[rb + 512];
                bf8_t b2 = *(const bf8_t*)&sW[rb + 1024];
                ar0 = __builtin_amdgcn_mfma_f32_16x16x32_bf16(af0[ks], b0, ar0, 0, 0, 0);
                ar1 = __builtin_amdgcn_mfma_f32_16x16x32_bf16(af1[ks], b0, ar1, 0, 0, 0);
                az0 = __builtin_amdgcn_mfma_f32_16x16x32_bf16(af0[ks], b1, az0, 0, 0, 0);
                az1 = __builtin_amdgcn_mfma_f32_16x16x32_bf16(af1[ks], b1, az1, 0, 0, 0);
                if (ks < 2) {
                    axn0 = __builtin_amdgcn_mfma_f32_16x16x32_bf16(af0[ks], b2, axn0, 0, 0, 0);
                    axn1 = __builtin_amdgcn_mfma_f32_16x16x32_bf16(af1[ks], b2, axn1, 0, 0, 0);
                } else {
                    ahn0 = __builtin_amdgcn_mfma_f32_16x16x32_bf16(af0[ks], b2, ahn0, 0, 0, 0);
                    ahn1 = __builtin_amdgcn_mfma_f32_16x16x32_bf16(af1[ks], b2, ahn1, 0, 0, 0);
                }
            }
            #pragma unroll
            for (int rr = 0; rr < 4; rr++) {
                const int idx = tswz(kg * 4 + rr, w * 16 + row);
                {
                    const float r_ = sigm(ar0[rr] + br_[w]);
                    const float z_ = sigm(az0[rr] + bz_[w]);
                    const float n_ = tanh_f(axn0[rr] + bxn_[w] + r_ * (ahn0[rr] + bhn_[w]));
                    const float h_ = bf2f(bufA[idx]);
                    bufA[idx] = f2bf_hw((1.f - z_) * n_ + z_ * h_);
                }
                {
                    const float r_ = sigm(ar1[rr] + br_[w]);
                    const float z_ = sigm(az1[rr] + bz_[w]);
                    const float n_ = tanh_f(axn1[rr] + bxn_[w] + r_ * (ahn1[rr] + bhn_[w]));
                    const float h_ = bf2f(bufB[idx]);
                    bufB[idx] = f2bf_hw((1.f - z_) * n_ + z_ * h_);
                }
            }
        }
        // bulk store: four contiguous 1KB bursts
        const int r8 = lane >> 3, c8 = (lane & 7) * 8;
        bf8_t oA0 = *(const bf8_t*)&bufA[tswz(r8, c8)];
        bf8_t oA1 = *(const bf8_t*)&bufA[tswz(8 + r8, c8)];
        bf8_t oB0 = *(const bf8_t*)&bufB[tswz(r8, c8)];
        bf8_t oB1 = *(const bf8_t*)&bufB[tswz(8 + r8, c8)];
        *(bf8_t*)(msg + (size_t)base * 64 + r8 * 64 + c8) = oA0;
        *(bf8_t*)(msg + (size_t)base * 64 + (8 + r8) * 64 + c8) = oA1;
        *(bf8_t*)(msg + (size_t)(base + 16) * 64 + r8 * 64 + c8) = oB0;
        *(bf8_t*)(msg + (size_t)(base + 16) * 64 + (8 + r8) * 64 + c8) = oB1;
    }
}

__launch_bounds__(256, 1)
__global__ void k_lstm(const int* __restrict__ dst_s, const u16* __restrict__ nfeat_new,
                       const u16* __restrict__ wpack, const float* __restrict__ bb,
                       const float* __restrict__ g_ln, const float* __restrict__ b_ln,
                       u16* __restrict__ efeat, u16* __restrict__ equery) {
    __shared__ u16 sW[32768];
    __shared__ u16 sBuf[4][1024];
    const int tid = threadIdx.x;
    const int lane = tid & 63;
    const int wv = tid >> 6;
    {
        const uint4* gsrc = (const uint4*)wpack;
        uint4* ldst = (uint4*)sW;
        #pragma unroll
        for (int i = 0; i < 16; i++) ldst[tid + i * 256] = gsrc[tid + i * 256];
    }
    __syncthreads();

    const int row = lane & 15, kg = lane >> 4;
    u16* buf = &sBuf[wv][0];
    float lgv[4], lbv[4];
    #pragma unroll
    for (int w = 0; w < 4; w++) { lgv[w] = g_ln[w * 16 + row]; lbv[w] = b_ln[w * 16 + row]; }

    const int NCH = EN / 16;
    const int stride = gridDim.x * 4;
    int ch = blockIdx.x * 4 + wv;
    bf8_t pn0 = {}, pn1 = {}, pe0 = {}, pe1 = {};
    if (ch < NCH) {
        const int de = dst_s[ch * 16 + row];
        pn0 = *(const bf8_t*)(nfeat_new + (size_t)de * 64 + kg * 8);
        pn1 = *(const bf8_t*)(nfeat_new + (size_t)de * 64 + 32 + kg * 8);
        pe0 = *(const bf8_t*)(efeat + (size_t)(ch * 16 + row) * 64 + kg * 8);
        pe1 = *(const bf8_t*)(efeat + (size_t)(ch * 16 + row) * 64 + 32 + kg * 8);
    }

    for (; ch < NCH; ch += stride) {
        const int base = ch * 16;
        const int e = base + row;
        bf8_t af[4];
        af[0] = pn0;
        af[1] = pn1;
        af[2] = pe0;
        af[3] = pe1;
        // stage equery-old into the wave tile (swizzled)
        {
            bf8_t q0 = *(const bf8_t*)(equery + (size_t)e * 64 + kg * 8);
            bf8_t q1 = *(const bf8_t*)(equery + (size_t)e * 64 + 32 + kg * 8);
            *(bf8_t*)&buf[tswz(row, kg * 8)] = q0;
            *(bf8_t*)&buf[tswz(row, kg * 8 + 32)] = q1;
        }
        // prefetch next chunk's nfeat_new gather (hidden under the gate loop)
        {
            const int nch = ch + stride;
            if (nch < NCH) {
                const int de = dst_s[nch * 16 + row];
                pn0 = *(const bf8_t*)(nfeat_new + (size_t)de * 64 + kg * 8);
                pn1 = *(const bf8_t*)(nfeat_new + (size_t)de * 64 + 32 + kg * 8);
            }
        }

        // hc[w][rr] = packed (bf16 hh, bf16 cc); LN sums stay exact f32
        unsigned hc[4][4];
        float sh[4] = {0, 0, 0, 0}, sh2[4] = {0, 0, 0, 0};
        float sc[4] = {0, 0, 0, 0}, sc2[4] = {0, 0, 0, 0};

        #pragma unroll
        for (int w = 0; w < 4; w++) {
            facc_t ai = {0.f, 0.f, 0.f, 0.f}, afv = ai, ag = ai, ao = ai;
            #pragma unroll
            for (int ks = 0; ks < 4; ks++) {
                const int rb = (ks * 16 + w * 4) * 512 + lane * 8;
                bf8_t b0 = *(const bf8_t*)&sW[rb];
                bf8_t b1 = *(const bf8_t*)&sW[rb + 512];
                bf8_t b2 = *(const bf8_t*)&sW[rb + 1024];
                bf8_t b3 = *(const bf8_t*)&sW[rb + 1536];
                ai  = __builtin_amdgcn_mfma_f32_16x16x32_bf16(af[ks], b0, ai, 0, 0, 0);
                afv = __builtin_amdgcn_mfma_f32_16x16x32_bf16(af[ks], b1, afv, 0, 0, 0);
                ag  = __builtin_amdgcn_mfma_f32_16x16x32_bf16(af[ks], b2, ag, 0, 0, 0);
                ao  = __builtin_amdgcn_mfma_f32_16x16x32_bf16(af[ks], b3, ao, 0, 0, 0);
            }
            const int d = w * 16 + row;
            const float bi = bb[d], bf_ = bb[64 + d], bg = bb[128 + d], bo = bb[192 + d];
            #pragma unroll
            for (int rr = 0; rr < 4; rr++) {
                const int idx = tswz(kg * 4 + rr, d);
                const float eq = bf2f(buf[idx]);
                const float ci = sigm(ai[rr] + bi);
                const float cf = sigm(afv[rr] + bf_);
                const float cg = tanh_f(ag[rr] + bg);
                const float co = sigm(ao[rr] + bo);
                const float c_ = cf * eq + ci * cg;
                const float h_ = co * tanh_f(c_);
                hc[w][rr] = cvtpk(h_, c_);
                sh[rr] += h_; sh2[rr] += h_ * h_;
                sc[rr] += c_; sc2[rr] += c_ * c_;
            }
        }
        #pragma unroll
        for (int off = 1; off < 16; off <<= 1) {
            #pragma unroll
            for (int rr = 0; rr < 4; rr++) {
                sh[rr] += __shfl_xor(sh[rr], off, 64);
                sh2[rr] += __shfl_xor(sh2[rr], off, 64);
                sc[rr] += __shfl_xor(sc[rr], off, 64);
                sc2[rr] += __shfl_xor(sc2[rr], off, 64);
            }
        }
        float hm[4], hrs[4], cm[4], crs[4];
        #pragma unroll
        for (int rr = 0; rr < 4; rr++) {
            hm[rr] = sh[rr] * (1.f / 64.f);
            hrs[rr] = rsqrtf(sh2[rr] * (1.f / 64.f) - hm[rr] * hm[rr] + EPS_);
            cm[rr] = sc[rr] * (1.f / 64.f);
            crs[rr] = rsqrtf(sc2[rr] * (1.f / 64.f) - cm[rr] * cm[rr] + EPS_);
        }
        // prefetch next chunk's efeat rows (hidden under the two output passes)
        {
            const int nch = ch + stride;
            if (nch < NCH) {
                const size_t ne = (size_t)(nch * 16 + row) * 64;
                pe0 = *(const bf8_t*)(efeat + ne + kg * 8);
                pe1 = *(const bf8_t*)(efeat + ne + 32 + kg * 8);
            }
        }
        // pass 1: equery-new in place (cc = hi half of hc), bulk store
        #pragma unroll
        for (int w = 0; w < 4; w++) {
            #pragma unroll
            for (int rr = 0; rr < 4; rr++) {
                const int idx = tswz(kg * 4 + rr, w * 16 + row);
                const float eqo = bf2f(buf[idx]);
                const float c_ = bf2f((u16)(hc[w][rr] >> 16));
                buf[idx] = f2bf_hw(eqo + (c_ - cm[rr]) * crs[rr] * lgv[w] + lbv[w]);
            }
        }
        {
            const int r8 = lane >> 3, c8 = (lane & 7) * 8;
            bf8_t o0 = *(const bf8_t*)&buf[tswz(r8, c8)];
            bf8_t o1 = *(const bf8_t*)&buf[tswz(8 + r8, c8)];
            *(bf8_t*)(equery + (size_t)base * 64 + r8 * 64 + c8) = o0;
            *(bf8_t*)(equery + (size_t)base * 64 + (8 + r8) * 64 + c8) = o1;
        }
        // restage efeat-old (still in af[2..3])
        *(bf8_t*)&buf[tswz(row, kg * 8)] = af[2];
        *(bf8_t*)&buf[tswz(row, kg * 8 + 32)] = af[3];
        // pass 2: efeat-new in place (hh = lo half of hc), bulk store
        #pragma unroll
        for (int w = 0; w < 4; w++) {
            #pragma unroll
            for (int rr = 0; rr < 4; rr++) {
                const int idx = tswz(kg * 4 + rr, w * 16 + row);
                const float efo = bf2f(buf[idx]);
                const float h_ = bf2f((u16)(hc[w][rr] & 0xFFFFu));
                buf[idx] = f2bf_hw(efo + (h_ - hm[rr]) * hrs[rr] * lgv[w] + lbv[w]);
            }
        }
        {
            const int r8 = lane >> 3, c8 = (lane & 7) * 8;
            bf8_t o0 = *(const bf8_t*)&buf[tswz(r8, c8)];
            bf8_t o1 = *(const bf8_t*)&buf[tswz(8 + r8, c8)];
            *(bf8_t*)(efeat + (size_t)base * 64 + r8 * 64 + c8) = o0;
            *(bf8_t*)(efeat + (size_t)base * 64 + (8 + r8) * 64 + c8) = o1;
        }
    }
}

// k_node: msg is CSR-ordered -> the aggregation loop reads CONTIGUOUS rows.
__launch_bounds__(256)
__global__ void k_node(const int* __restrict__ row_ptr,
                       const u16* __restrict__ msg, const float* __restrict__ avg_sum,
                       const u16* __restrict__ wpack, const float* __restrict__ pb,
                       const float* __restrict__ g_ln, const float* __restrict__ b_ln,
                       u16* __restrict__ nfeat, u16* __restrict__ nfeat_new) {
    __shared__ u16 sAgg[16 * 280];
    __shared__ float sS[16], sT[16];
    __shared__ float sRed[4][16][2];
    const int lane = threadIdx.x & 63;
    const int w = threadIdx.x >> 6;
    const int base = blockIdx.x * 16;
    const float avg = avg_sum[0] * (1.f / (float)NN);

    bf8_t bw[8][3];
    #pragma unroll
    for (int ks = 0; ks < 8; ks++) {
        #pragma unroll
        for (int y = 0; y < 3; y++)
            bw[ks][y] = ((const bf8_t*)wpack)[((ks * 3 + y) * 4 + w) * 64 + lane];
    }

    float samp[4], satt[4];
    #pragma unroll
    for (int q = 0; q < 4; q++) {
        const int m = w * 4 + q;
        const int v = base + m;
        const int rs = row_ptr[v], re = row_ptr[v + 1];
        float s = 0.f, s2 = 0.f, mx = -INFINITY, mn = INFINITY;
        for (int i = rs; i < re; i++) {
            const float mv = bf2f(msg[(size_t)i * 64 + lane]);
            s += mv; s2 += mv * mv; mx = fmaxf(mx, mv); mn = fminf(mn, mv);
        }
        const float deg = (float)(re - rs);
        const float dsafe = fmaxf(deg, 1.f);
        const float mean = s / dsafe;
        const float sq = s2 / dsafe;
        const bool has = (re - rs) > 0;
        const float amx = has ? mx : 0.f;
        const float amn = has ? mn : 0.f;
        const float astd = sqrtf(fmaxf(sq - mean * mean, 0.f) + EPS_);
        uint2 pk;
        pk.x = cvtpk(mean, amx);
        pk.y = cvtpk(amn, astd);
        *(uint2*)&sAgg[m * 280 + lane * 4] = pk;
        const float ld = logf(deg + 1.f);
        samp[q] = ld / avg;
        satt[q] = ld > 0.f ? avg / fmaxf(ld, EPS_) : 0.f;
    }
    if (lane == 0) {
        #pragma unroll
        for (int q = 0; q < 4; q++) { sS[w * 4 + q] = samp[q]; sT[w * 4 + q] = satt[q]; }
    }
    __syncthreads();

    facc_t c0 = {0.f, 0.f, 0.f, 0.f}, c1 = c0, c2 = c0;
    const int arow = lane & 15, acol = (lane >> 4) * 8;
    #pragma unroll
    for (int ks = 0; ks < 8; ks++) {
        bf8_t af = *(const bf8_t*)&sAgg[arow * 280 + ks * 32 + acol];
        c0 = __builtin_amdgcn_mfma_f32_16x16x32_bf16(af, bw[ks][0], c0, 0, 0, 0);
        c1 = __builtin_amdgcn_mfma_f32_16x16x32_bf16(af, bw[ks][1], c1, 0, 0, 0);
        c2 = __builtin_amdgcn_mfma_f32_16x16x32_bf16(af, bw[ks][2], c2, 0, 0, 0);
    }

    const int d = w * 16 + (lane & 15);
    const float pbl = pb[d], lg = g_ln[d], lb = b_ln[d];
    float nf[4];
    #pragma unroll
    for (int rr = 0; rr < 4; rr++) {
        const int m = (lane >> 4) * 4 + rr;
        nf[rr] = pbl + c0[rr] + sS[m] * c1[rr] + sT[m] * c2[rr];
        nfeat_new[(size_t)(base + m) * 64 + d] = f2bf_hw(nf[rr]);
    }
    float ps[4], ps2[4];
    #pragma unroll
    for (int rr = 0; rr < 4; rr++) { ps[rr] = nf[rr]; ps2[rr] = nf[rr] * nf[rr]; }
    #pragma unroll
    for (int off = 1; off < 16; off <<= 1) {
        #pragma unroll
        for (int rr = 0; rr < 4; rr++) {
            ps[rr] += __shfl_xor(ps[rr], off, 64);
            ps2[rr] += __shfl_xor(ps2[rr], off, 64);
        }
    }
    if ((lane & 15) == 0) {
        #pragma unroll
        for (int rr = 0; rr < 4; rr++) {
            const int m = (lane >> 4) * 4 + rr;
            sRed[w][m][0] = ps[rr];
            sRed[w][m][1] = ps2[rr];
        }
    }
    __syncthreads();
    #pragma unroll
    for (int rr = 0; rr < 4; rr++) {
        const int m = (lane >> 4) * 4 + rr;
        float ts = 0.f, ts2 = 0.f;
        #pragma unroll
        for (int w2 = 0; w2 < 4; w2++) { ts += sRed[w2][m][0]; ts2 += sRed[w2][m][1]; }
        const float mean = ts * (1.f / 64.f);
        const float var = ts2 * (1.f / 64.f) - mean * mean;
        const size_t off = (size_t)(base + m) * 64 + d;
        nfeat[off] = f2bf_hw(bf2f(nfeat[off]) + (nf[rr] - mean) * rsqrtf(var + EPS_) * lg + lb);
    }
}

__global__ void k_snap(const int* __restrict__ tgt, const int* __restrict__ src,
                       const int* __restrict__ inv,
                       const u16* __restrict__ efeat, const u16* __restrict__ equery,
                       const u16* __restrict__ nfeat,
                       float* jk_e, float* jk_q, float* jk_n) {
    int t = blockIdx.x, d = threadIdx.x;
    int e = tgt[t];
    int pos = inv[e];
    jk_e[t * 64 + d] = bf2f(efeat[(size_t)pos * 64 + d]);
    jk_q[t * 64 + d] = bf2f(equery[(size_t)pos * 64 + d]);
    int v = src[e];
    jk_n[t * 64 + d] = bf2f(nfeat[v * 64 + d]);
}

// ---------------- output head ----------------

__global__ void k_jk(const float* __restrict__ jk_e, const float* __restrict__ jk_q, const float* __restrict__ jk_n,
                     const float* __restrict__ ejk_w, const float* __restrict__ ejk_b,
                     const float* __restrict__ qjk_w, const float* __restrict__ qjk_b,
                     const float* __restrict__ njk_w, const float* __restrict__ njk_b,
                     float* ejk_o, float* qjk_o, float* njk_o) {
    int t = blockIdx.x, d = threadIdx.x;
    float ae = ejk_b[d], aq = qjk_b[d], an_ = njk_b[d];
    for (int l = 0; l < 3; l++) {
        for (int dd = 0; dd < 64; dd++) {
            int k = l * 64 + dd;
            ae += jk_e[(l * 64 + t) * 64 + dd] * ejk_w[k * 64 + d];
            aq += jk_q[(l * 64 + t) * 64 + dd] * qjk_w[k * 64 + d];
            an_ += jk_n[(l * 64 + t) * 64 + dd] * njk_w[k * 64 + d];
        }
    }
    ejk_o[t * 64 + d] = ae;
    qjk_o[t * 64 + d] = aq;
    njk_o[t * 64 + d] = an_;
}

__global__ void k_final(const float* __restrict__ ejk_o, const float* __restrict__ qjk_o,
                        const float* __restrict__ njk_o,
                        const float* __restrict__ fc_w, const float* __restrict__ fc_b,
                        float* out) {
    int b = blockIdx.x, d = threadIdx.x;
    int t0 = 2 * b, t1 = 2 * b + 1;
    float r = ejk_o[t0 * 64 + d] * fc_w[d] + qjk_o[t0 * 64 + d] * fc_w[64 + d]
            + njk_o[t0 * 64 + d] * fc_w[128 + d] + njk_o[t1 * 64 + d] * fc_w[192 + d];
    float lf = ejk_o[t1 * 64 + d] * fc_w[d] + qjk_o[t1 * 64 + d] * fc_w[64 + d]
             + njk_o[t1 * 64 + d] * fc_w[128 + d] + njk_o[t0 * 64 + d] * fc_w[192 + d];
    #pragma unroll
    for (int off = 32; off > 0; off >>= 1) { r += __shfl_xor(r, off, 64); lf += __shfl_xor(lf, off, 64); }
    if (d == 0) out[b] = fmaxf(r + fc_b[0], lf + fc_b[0]);
}

// ---------------- host launcher ----------------

extern "C" void kernel_launch(void* const* d_in, const int* in_sizes, int n_in,
                              void* d_out, int out_size, void* d_ws, size_t ws_size,
                              hipStream_t stream) {
    const int* src   = (const int*)d_in[0];
    const int* dst   = (const int*)d_in[1];
    const int* etype = (const int*)d_in[2];
    const int* egid  = (const int*)d_in[3];
    const int* tgt   = (const int*)d_in[4];
    const float* query_emb = (const float*)d_in[6];
    const float* eqp_w = (const float*)d_in[7];
    const float* eqp_b = (const float*)d_in[8];
    const float* rel_w = (const float*)d_in[9];
    const float* gru_wx = (const float*)d_in[10];
    const float* gru_wh = (const float*)d_in[11];
    const float* gru_bx = (const float*)d_in[12];
    const float* gru_bh = (const float*)d_in[13];
    const float* pna_w = (const float*)d_in[14];
    const float* pna_b = (const float*)d_in[15];
    const float* lstm_wx = (const float*)d_in[16];
    const float* lstm_wh = (const float*)d_in[17];
    const float* lstm_b = (const float*)d_in[18];
    const float* ln_g = (const float*)d_in[19];
    const float* ln_b = (const float*)d_in[20];
    const float* ejk_w = (const float*)d_in[21];
    const float* ejk_b = (const float*)d_in[22];
    const float* njk_w = (const float*)d_in[23];
    const float* njk_b = (const float*)d_in[24];
    const float* qjk_w = (const float*)d_in[25];
    const float* qjk_b = (const float*)d_in[26];
    const float* fc_w = (const float*)d_in[27];
    const float* fc_b = (const float*)d_in[28];

    u16* q16 = (u16*)d_ws;
    u16* equery = q16;     q16 += (size_t)EN * 64;
    u16* efeat = q16;      q16 += (size_t)EN * 64;
    u16* msg = q16;        q16 += (size_t)EN * 64;
    u16* nfeat = q16;      q16 += (size_t)NN * 64;
    u16* nfeat_new = q16;  q16 += (size_t)NN * 64;
    u16* wpg = q16;        q16 += 3 * 24576;
    u16* wpl = q16;        q16 += 3 * 32768;
    u16* wpp = q16;        q16 += 3 * 49152;
    u16* msg_row = q16;    q16 += 32 * 64;
    q16 += 32;  // alignment pad
    float* p = (float*)q16;
    float* tgt_q = p;     p += 64 * 64;
    float* eq_g = p;      p += 32 * 64;
    float* jk_e = p;      p += 3 * 64 * 64;
    float* jk_q = p;      p += 3 * 64 * 64;
    float* jk_n = p;      p += 3 * 64 * 64;
    float* ejk_o = p;     p += 64 * 64;
    float* qjk_o = p;     p += 64 * 64;
    float* njk_o = p;     p += 64 * 64;
    float* avg_sum = p;   p += 64;
    int* ip = (int*)p;
    int* row_ptr = ip; ip += NN + 1;
    int* fillp = ip;   ip += NN;
    int* cnt = ip;     ip += NN;
    int* outcnt = ip;  ip += NN;
    int* inv = ip;     ip += EN;
    int* src_s = ip;   ip += EN;
    int* dst_s = ip;   ip += EN;
    int* ty_s = ip;    ip += EN;
    int* gid_s = ip;   ip += EN;
    int* bsum = ip;    ip += 64;
    int* boff = ip;    ip += 64;
    if ((size_t)((char*)ip - (char*)d_ws) > ws_size) return;

    k_init<<<4096, 256, 0, stream>>>(efeat, nfeat, cnt, outcnt, avg_sum);
    k_count<<<1024, 256, 0, stream>>>(src, dst, cnt, outcnt);
    k_scan1<<<40, 1024, 0, stream>>>(cnt, row_ptr, bsum);
    k_scan2<<<1, 64, 0, stream>>>(bsum, boff, row_ptr);
    k_scan3<<<40, 1024, 0, stream>>>(row_ptr, fillp, boff);
    k_fill<<<1024, 256, 0, stream>>>(src, dst, etype, egid, fillp, inv,
                                     src_s, dst_s, ty_s, gid_s);
    k_avg<<<(NN + 255) / 256, 256, 0, stream>>>(outcnt, avg_sum);
    k_tgt<<<64, 64, 0, stream>>>(tgt, etype, inv, query_emb, tgt_q, efeat);
    k_eqg<<<32, 64, 0, stream>>>(tgt_q, eqp_w, eqp_b, eq_g);
    k_equery<<<8192, 256, 0, stream>>>(gid_s, eq_g, equery);
    k_pack_gru<<<dim3(16, 3), 256, 0, stream>>>(gru_wx, gru_wh, wpg);
    k_pack_lstm<<<dim3(16, 3), 256, 0, stream>>>(lstm_wx, lstm_wh, wpl);
    k_pack_pna<<<dim3(24, 3), 256, 0, stream>>>(pna_w, wpp);

    for (int l = 0; l < 3; l++) {
        if (l == 0) {
            k_gru0_rows<<<32, 64, 0, stream>>>(eq_g, gru_wx, gru_bx, gru_bh, msg_row);
            k_gru0_scatter<<<4096, 256, 0, stream>>>(gid_s, msg_row, msg);
            k_gru0_fix<<<64, 64, 0, stream>>>(tgt, etype, inv, equery, efeat, rel_w,
                gru_wx, gru_wh, gru_bx, gru_bh, msg);
        } else {
            k_gru<<<512, 256, 0, stream>>>(src_s, ty_s, nfeat, equery, efeat,
                rel_w + (size_t)l * NR * 64, wpg + (size_t)l * 24576,
                gru_bx + (size_t)l * 192, gru_bh + (size_t)l * 192, msg);
        }
        k_node<<<NN / 16, 256, 0, stream>>>(row_ptr, msg, avg_sum,
            wpp + (size_t)l * 49152, pna_b + (size_t)l * 64,
            ln_g + (size_t)l * 64, ln_b + (size_t)l * 64, nfeat, nfeat_new);
        k_lstm<<<512, 256, 0, stream>>>(dst_s, nfeat_new, wpl + (size_t)l * 32768,
            lstm_b + (size_t)l * 256,
            ln_g + (size_t)l * 64, ln_b + (size_t)l * 64, efeat, equery);
        k_snap<<<64, 64, 0, stream>>>(tgt, src, inv, efeat, equery, nfeat,
            jk_e + l * 4096, jk_q + l * 4096, jk_n + l * 4096);
    }

    k_jk<<<64, 64, 0, stream>>>(jk_e, jk_q, jk_n, ejk_w, ejk_b, qjk_w, qjk_b, njk_w, njk_b,
                                ejk_o, qjk_o, njk_o);
    k_final<<<32, 64, 0, stream>>>(ejk_o, qjk_o, njk_o, fc_w, fc_b, (float*)d_out);
}

// Round 22
// 653.497 us; speedup vs baseline: 1.1743x; 1.0387x over previous
//
#include <hip/hip_runtime.h>
#include <math.h>

#define EN 256000
#define NN 40000
#define NR 474
#define EPS_ 1e-5f

typedef unsigned short u16;
typedef __attribute__((ext_vector_type(4))) float f4_t;
typedef __attribute__((ext_vector_type(8))) short bf8_t;
typedef __attribute__((ext_vector_type(4))) float facc_t;

__device__ __forceinline__ float sigm(float x) { return 1.f / (1.f + __expf(-x)); }
__device__ __forceinline__ float tanh_f(float x) { float e = __expf(2.f * x); return 1.f - 2.f / (e + 1.f); }

__device__ __forceinline__ u16 f2bf(float f) {
    unsigned u = __float_as_uint(f);
    return (u16)((u + 0x7FFFu + ((u >> 16) & 1u)) >> 16);
}
__device__ __forceinline__ unsigned cvtpk(float lo, float hi) {
    unsigned r;
    asm("v_cvt_pk_bf16_f32 %0, %1, %2" : "=v"(r) : "v"(lo), "v"(hi));
    return r;
}
__device__ __forceinline__ u16 f2bf_hw(float v) { return (u16)cvtpk(v, v); }
__device__ __forceinline__ float bf2f(u16 u) { return __uint_as_float(((unsigned)u) << 16); }

__device__ __forceinline__ bf8_t pack8(f4_t a, f4_t b) {
    union { unsigned u[4]; bf8_t v; } r;
    r.u[0] = cvtpk(a[0], a[1]);
    r.u[1] = cvtpk(a[2], a[3]);
    r.u[2] = cvtpk(b[0], b[1]);
    r.u[3] = cvtpk(b[2], b[3]);
    return r.v;
}
__device__ __forceinline__ void unpk8(bf8_t v, f4_t& a, f4_t& b) {
    a[0] = bf2f((u16)v[0]); a[1] = bf2f((u16)v[1]); a[2] = bf2f((u16)v[2]); a[3] = bf2f((u16)v[3]);
    b[0] = bf2f((u16)v[4]); b[1] = bf2f((u16)v[5]); b[2] = bf2f((u16)v[6]); b[3] = bf2f((u16)v[7]);
}

// swizzled u16 index into a 16x64 wave tile (see round-11 analysis)
__device__ __forceinline__ int tswz(int r, int u) {
    return r * 64 + (u ^ (((r >> 2) & 3) << 4));
}

// ---------------- init / graph prep ----------------

__global__ void k_init(u16* efeat, u16* nfeat, int* cnt, int* outcnt, float* avg_sum) {
    long total = (long)EN * 32;
    unsigned* ef = (unsigned*)efeat;
    unsigned* nf = (unsigned*)nfeat;
    for (long i = blockIdx.x * (long)blockDim.x + threadIdx.x; i < total; i += (long)gridDim.x * blockDim.x) {
        ef[i] = 0u;
        if (i < (long)NN * 32) nf[i] = 0u;
        if (i < NN) { cnt[i] = 0; outcnt[i] = 0; }
        if (i == 0) avg_sum[0] = 0.f;
    }
}

__global__ void k_count(const int* __restrict__ src, const int* __restrict__ dst, int* cnt, int* outcnt) {
    for (int e = blockIdx.x * blockDim.x + threadIdx.x; e < EN; e += gridDim.x * blockDim.x) {
        atomicAdd(&cnt[dst[e]], 1);
        atomicAdd(&outcnt[src[e]], 1);
    }
}

// 3-kernel device-wide exclusive scan
__global__ void k_scan1(const int* __restrict__ cnt, int* __restrict__ row_ptr, int* __restrict__ bsum) {
    __shared__ int tmp[1024];
    const int b = blockIdx.x, t = threadIdx.x;
    const int idx = b * 1024 + t;
    const int v = (idx < NN) ? cnt[idx] : 0;
    tmp[t] = v;
    __syncthreads();
    for (int off = 1; off < 1024; off <<= 1) {
        int u = (t >= off) ? tmp[t - off] : 0;
        __syncthreads();
        tmp[t] += u;
        __syncthreads();
    }
    if (idx < NN) row_ptr[idx] = tmp[t] - v;
    if (t == 1023) bsum[b] = tmp[t];
}

__global__ void k_scan2(const int* __restrict__ bsum, int* __restrict__ boff, int* __restrict__ row_ptr) {
    const int t = threadIdx.x;
    const int v = (t < 40) ? bsum[t] : 0;
    int s = v;
    #pragma unroll
    for (int off = 1; off < 64; off <<= 1) {
        int u = __shfl_up(s, off, 64);
        if (t >= off) s += u;
    }
    if (t < 40) boff[t] = s - v;
    if (t == 63) row_ptr[NN] = s;
}

__global__ void k_scan3(int* __restrict__ row_ptr, int* __restrict__ fillp, const int* __restrict__ boff) {
    const int idx = blockIdx.x * 1024 + threadIdx.x;
    if (idx < NN) {
        const int r = row_ptr[idx] + boff[blockIdx.x];
        row_ptr[idx] = r;
        fillp[idx] = r;
    }
}

// CSR permutation: pos = inv[e]; all per-edge feature arrays live in dst-sorted
// order. Also emits coalescable per-position copies of src/dst/etype/egid.
__global__ void k_fill(const int* __restrict__ src, const int* __restrict__ dst,
                       const int* __restrict__ etype, const int* __restrict__ egid,
                       int* fillp, int* __restrict__ inv,
                       int* __restrict__ src_s, int* __restrict__ dst_s,
                       int* __restrict__ ty_s, int* __restrict__ gid_s) {
    for (int e = blockIdx.x * blockDim.x + threadIdx.x; e < EN; e += gridDim.x * blockDim.x) {
        const int de = dst[e];
        const int pos = atomicAdd(&fillp[de], 1);
        inv[e] = pos;
        src_s[pos] = src[e];
        dst_s[pos] = de;
        ty_s[pos] = etype[e];
        gid_s[pos] = egid[e];
    }
}

__global__ void k_avg(const int* __restrict__ outcnt, float* __restrict__ avg_sum) {
    int n = blockIdx.x * blockDim.x + threadIdx.x;
    float v = 0.f;
    if (n < NN) v = logf((float)outcnt[n] + 1.f);
    #pragma unroll
    for (int off = 32; off > 0; off >>= 1) v += __shfl_xor(v, off, 64);
    if ((threadIdx.x & 63) == 0) atomicAdd(avg_sum, v);
}

// Fused prep for the 32 graphs (was k_tgt + k_eqg + k_gru0_rows): each block's
// chain is block-local (target rows -> eq_g row -> layer-0 GRU msg row).
// Summation orders identical to the previous split kernels (bitwise-same).
__global__ void k_prep_small(const int* __restrict__ tgt, const int* __restrict__ etype,
                             const int* __restrict__ inv,
                             const float* __restrict__ query_emb,
                             const float* __restrict__ eqp_w, const float* __restrict__ eqp_b,
                             const float* __restrict__ gru_wx,
                             const float* __restrict__ gru_bx, const float* __restrict__ gru_bh,
                             float* __restrict__ tgt_q, u16* __restrict__ efeat,
                             float* __restrict__ eq_g, u16* __restrict__ msg_row) {
    __shared__ float sQ[128];
    __shared__ float sE[64];
    const int g = blockIdx.x, d = threadIdx.x;  // 32 x 64
    #pragma unroll
    for (int j = 0; j < 2; j++) {
        const int t = 2 * g + j;
        const int e = tgt[t];
        const int r = etype[e];
        const float v = query_emb[r * 64 + d];
        tgt_q[t * 64 + d] = v;
        efeat[(size_t)inv[e] * 64 + d] = f2bf(v);
        sQ[j * 64 + d] = v;
    }
    __syncthreads();
    float acc = eqp_b[d];
    for (int k = 0; k < 128; k++) acc += sQ[k] * eqp_w[k * 64 + d];
    eq_g[g * 64 + d] = acc;
    sE[d] = bf2f(f2bf(acc));
    __syncthreads();
    float ar = gru_bx[d], az = gru_bx[64 + d], an = gru_bx[128 + d];
    for (int k = 0; k < 64; k++) {
        const float x = sE[k];
        ar += x * gru_wx[k * 192 + d];
        az += x * gru_wx[k * 192 + 64 + d];
        an += x * gru_wx[k * 192 + 128 + d];
    }
    const float r = sigm(ar + gru_bh[d]);
    const float z = sigm(az + gru_bh[64 + d]);
    const float n = tanh_f(an + r * gru_bh[128 + d]);
    msg_row[g * 64 + d] = f2bf((1.f - z) * n);
}

// Fused broadcast (was k_equery + k_gru0_scatter): one EN-wide pass writes both
// equery (bf16 of eq_g row) and layer-0 msg, sharing the gid_s index stream.
__global__ void k_bcast(const int* __restrict__ gid_s, const float* __restrict__ eq_g,
                        const u16* __restrict__ msg_row,
                        u16* __restrict__ equery, u16* __restrict__ msg) {
    long total = (long)EN * 32;
    const unsigned* mr = (const unsigned*)msg_row;
    unsigned* m = (unsigned*)msg;
    unsigned* q = (unsigned*)equery;
    for (long i = blockIdx.x * (long)blockDim.x + threadIdx.x; i < total; i += (long)gridDim.x * blockDim.x) {
        const int e = (int)(i >> 5);
        const int dd = (int)(i & 31);
        const int g = gid_s[e];
        m[i] = mr[g * 32 + dd];
        const float a = eq_g[g * 64 + 2 * dd];
        const float b = eq_g[g * 64 + 2 * dd + 1];
        q[i] = cvtpk(a, b);
    }
}

__global__ void k_gru0_fix(const int* __restrict__ tgt, const int* __restrict__ etype,
                           const int* __restrict__ inv,
                           const u16* __restrict__ equery, const u16* __restrict__ efeat,
                           const float* __restrict__ relw,
                           const float* __restrict__ wx, const float* __restrict__ wh,
                           const float* __restrict__ bx, const float* __restrict__ bh,
                           u16* __restrict__ msg) {
    const int t = blockIdx.x, d = threadIdx.x;  // 64 x 64
    const int e = tgt[t];
    const int pos = inv[e];
    const int ty = etype[e];
    float ar = bx[d], az = bx[64 + d], an = bx[128 + d];
    float br = bh[d], bz = bh[64 + d], bn = bh[128 + d];
    for (int k = 0; k < 64; k++) {
        const float x = bf2f(equery[(size_t)pos * 64 + k]);
        const float h = bf2f(efeat[(size_t)pos * 64 + k]) * relw[ty * 64 + k];
        ar += x * wx[k * 192 + d];       br += h * wh[k * 192 + d];
        az += x * wx[k * 192 + 64 + d];  bz += h * wh[k * 192 + 64 + d];
        an += x * wx[k * 192 + 128 + d]; bn += h * wh[k * 192 + 128 + d];
    }
    const float r = sigm(ar + br);
    const float z = sigm(az + bz);
    const float n = tanh_f(an + r * bn);
    const float h_ = bf2f(efeat[(size_t)pos * 64 + d]) * relw[ty * 64 + d];
    msg[(size_t)pos * 64 + d] = f2bf_hw((1.f - z) * n + z * h_);
}

// ---------------- weight packing for MFMA (single fused dispatch) ----------------
// GRU: 3 sections (r, z, n); n = Wx_n for k<64, Wh_n for k>=64. LSTM/PNA as before.

__global__ void k_pack_all(const float* __restrict__ gwx, const float* __restrict__ gwh,
                           const float* __restrict__ lwx, const float* __restrict__ lwh,
                           const float* __restrict__ pw,
                           u16* __restrict__ wpg, u16* __restrict__ wpl, u16* __restrict__ wpp) {
    const int l = blockIdx.y;
    const float* wx = gwx + (size_t)l * 64 * 192;
    const float* wh = gwh + (size_t)l * 64 * 192;
    const float* lx = lwx + (size_t)l * 64 * 256;
    const float* lh = lwh + (size_t)l * 64 * 256;
    const float* pp = pw + (size_t)l * 768 * 64;
    u16* og = wpg + (size_t)l * 24576;
    u16* ol = wpl + (size_t)l * 32768;
    u16* op = wpp + (size_t)l * 49152;
    const int TOT = 24576 + 32768 + 49152;
    for (int idx0 = blockIdx.x * blockDim.x + threadIdx.x; idx0 < TOT; idx0 += gridDim.x * blockDim.x) {
        if (idx0 < 24576) {
            const int idx = idx0;
            int rec = idx >> 3, j = idx & 7;
            int lane = rec & 63, rw = rec >> 6;
            int g = rw % 3, ksw = rw / 3;
            int w = ksw & 3, ks = ksw >> 2;
            int k = ks * 32 + (lane >> 4) * 8 + j;
            int d = w * 16 + (lane & 15);
            float v;
            if (g == 0)      v = k < 64 ? wx[k * 192 + d]       : wh[(k - 64) * 192 + d];
            else if (g == 1) v = k < 64 ? wx[k * 192 + 64 + d]  : wh[(k - 64) * 192 + 64 + d];
            else             v = k < 64 ? wx[k * 192 + 128 + d] : wh[(k - 64) * 192 + 128 + d];
            og[idx] = f2bf(v);
        } else if (idx0 < 24576 + 32768) {
            const int idx = idx0 - 24576;
            int rec = idx >> 3, j = idx & 7;
            int lane = rec & 63, ksnt = rec >> 6;
            int nt = ksnt & 15, ks = ksnt >> 4;
            int k = ks * 32 + (lane >> 4) * 8 + j;
            int g = nt & 3, d = (nt >> 2) * 16 + (lane & 15);
            float v = k < 64 ? lx[k * 256 + g * 64 + d] : lh[(k - 64) * 256 + g * 64 + d];
            ol[idx] = f2bf(v);
        } else {
            const int idx = idx0 - 24576 - 32768;
            int rec = idx >> 3, j = idx & 7;
            int lane = rec & 63, f = rec >> 6;
            int w = f & 3, ys = f >> 2;
            int y = ys % 3, ks = ys / 3;
            int k = ks * 32 + (lane >> 4) * 8 + j;
            int sec = k & 3, dfeat = k >> 2;
            int d = w * 16 + (lane & 15);
            op[idx] = f2bf(pp[(size_t)(y * 256 + sec * 64 + dfeat) * 64 + d]);
        }
    }
}

// ---------------- per-layer edge kernels (CSR-sorted edge order) ----------------

__launch_bounds__(256, 1)
__global__ void k_gru(const int* __restrict__ src_s, const int* __restrict__ ty_s,
                      const u16* __restrict__ nfeat, const u16* __restrict__ equery,
                      const u16* __restrict__ efeat, const float* __restrict__ relw,
                      const u16* __restrict__ wpack,
                      const float* __restrict__ bx, const float* __restrict__ bh,
                      u16* __restrict__ msg) {
    __shared__ u16 sW[24576];
    __shared__ u16 sBuf[4][2048];
    const int tid = threadIdx.x;
    const int lane = tid & 63;
    const int wv = tid >> 6;
    {
        const uint4* gsrc = (const uint4*)wpack;
        uint4* ldst = (uint4*)sW;
        #pragma unroll
        for (int i = 0; i < 12; i++) ldst[tid + i * 256] = gsrc[tid + i * 256];
    }
    __syncthreads();

    const int row = lane & 15, kg = lane >> 4;
    u16* bufA = &sBuf[wv][0];
    u16* bufB = &sBuf[wv][1024];
    float br_[4], bz_[4], bxn_[4], bhn_[4];
    #pragma unroll
    for (int w = 0; w < 4; w++) {
        const int d = w * 16 + row;
        br_[w] = bx[d] + bh[d];
        bz_[w] = bx[64 + d] + bh[64 + d];
        bxn_[w] = bx[128 + d];
        bhn_[w] = bh[128 + d];
    }

    const int NCH = EN / 32;
    const int stride = gridDim.x * 4;
    int ch = blockIdx.x * 4 + wv;
    bf8_t pa0 = {}, pa1 = {}, pb0 = {}, pb1 = {};
    if (ch < NCH) {
        const int s0 = src_s[ch * 32 + row];
        const int s1 = src_s[ch * 32 + 16 + row];
        pa0 = *(const bf8_t*)(nfeat + (size_t)s0 * 64 + kg * 8);
        pa1 = *(const bf8_t*)(nfeat + (size_t)s0 * 64 + 32 + kg * 8);
        pb0 = *(const bf8_t*)(nfeat + (size_t)s1 * 64 + kg * 8);
        pb1 = *(const bf8_t*)(nfeat + (size_t)s1 * 64 + 32 + kg * 8);
    }

    for (; ch < NCH; ch += stride) {
        const int base = ch * 32;
        const int e0 = base + row;
        const int e1 = base + 16 + row;
        const int ty0 = ty_s[e0], ty1 = ty_s[e1];
        bf8_t af0[4], af1[4];
        {
            bf8_t q0 = *(const bf8_t*)(equery + (size_t)e0 * 64 + kg * 8);
            bf8_t q1 = *(const bf8_t*)(equery + (size_t)e0 * 64 + 32 + kg * 8);
            f4_t na, nb, qa, qb;
            unpk8(pa0, na, nb); unpk8(q0, qa, qb);
            af0[0] = pack8(na + qa, nb + qb);
            unpk8(pa1, na, nb); unpk8(q1, qa, qb);
            af0[1] = pack8(na + qa, nb + qb);
        }
        {
            bf8_t q0 = *(const bf8_t*)(equery + (size_t)e1 * 64 + kg * 8);
            bf8_t q1 = *(const bf8_t*)(equery + (size_t)e1 * 64 + 32 + kg * 8);
            f4_t na, nb, qa, qb;
            unpk8(pb0, na, nb); unpk8(q0, qa, qb);
            af1[0] = pack8(na + qa, nb + qb);
            unpk8(pb1, na, nb); unpk8(q1, qa, qb);
            af1[1] = pack8(na + qa, nb + qb);
        }
        {
            bf8_t x0 = *(const bf8_t*)(efeat + (size_t)e0 * 64 + kg * 8);
            bf8_t x1 = *(const bf8_t*)(efeat + (size_t)e0 * 64 + 32 + kg * 8);
            f4_t r0 = *(const f4_t*)(relw + ty0 * 64 + kg * 8);
            f4_t r1 = *(const f4_t*)(relw + ty0 * 64 + kg * 8 + 4);
            f4_t r2 = *(const f4_t*)(relw + ty0 * 64 + 32 + kg * 8);
            f4_t r3 = *(const f4_t*)(relw + ty0 * 64 + 32 + kg * 8 + 4);
            f4_t ea, eb;
            unpk8(x0, ea, eb);
            af0[2] = pack8(ea * r0, eb * r1);
            unpk8(x1, ea, eb);
            af0[3] = pack8(ea * r2, eb * r3);
        }
        {
            bf8_t x0 = *(const bf8_t*)(efeat + (size_t)e1 * 64 + kg * 8);
            bf8_t x1 = *(const bf8_t*)(efeat + (size_t)e1 * 64 + 32 + kg * 8);
            f4_t r0 = *(const f4_t*)(relw + ty1 * 64 + kg * 8);
            f4_t r1 = *(const f4_t*)(relw + ty1 * 64 + kg * 8 + 4);
            f4_t r2 = *(const f4_t*)(relw + ty1 * 64 + 32 + kg * 8);
            f4_t r3 = *(const f4_t*)(relw + ty1 * 64 + 32 + kg * 8 + 4);
            f4_t ea, eb;
            unpk8(x0, ea, eb);
            af1[2] = pack8(ea * r0, eb * r1);
            unpk8(x1, ea, eb);
            af1[3] = pack8(ea * r2, eb * r3);
        }
        // prefetch next chunk's nfeat gathers
        {
            const int nch = ch + stride;
            if (nch < NCH) {
                const int s0 = src_s[nch * 32 + row];
                const int s1 = src_s[nch * 32 + 16 + row];
                pa0 = *(const bf8_t*)(nfeat + (size_t)s0 * 64 + kg * 8);
                pa1 = *(const bf8_t*)(nfeat + (size_t)s0 * 64 + 32 + kg * 8);
                pb0 = *(const bf8_t*)(nfeat + (size_t)s1 * 64 + kg * 8);
                pb1 = *(const bf8_t*)(nfeat + (size_t)s1 * 64 + 32 + kg * 8);
            }
        }
        // stage h into the two wave tiles (swizzled b128 writes)
        *(bf8_t*)&bufA[tswz(row, kg * 8)] = af0[2];
        *(bf8_t*)&bufA[tswz(row, kg * 8 + 32)] = af0[3];
        *(bf8_t*)&bufB[tswz(row, kg * 8)] = af1[2];
        *(bf8_t*)&bufB[tswz(row, kg * 8 + 32)] = af1[3];

        #pragma unroll
        for (int w = 0; w < 4; w++) {
            facc_t ar0 = {0.f, 0.f, 0.f, 0.f}, az0 = ar0, axn0 = ar0, ahn0 = ar0;
            facc_t ar1 = ar0, az1 = ar0, axn1 = ar0, ahn1 = ar0;
            #pragma unroll
            for (int ks = 0; ks < 4; ks++) {
                const int rb = ((ks * 4 + w) * 3) * 512 + lane * 8;
                bf8_t b0 = *(const bf8_t*)&sW[rb];
                bf8_t b1 = *(const bf8_t*)&sW[rb + 512];
                bf8_t b2 = *(const bf8_t*)&sW[rb + 1024];
                ar0 = __builtin_amdgcn_mfma_f32_16x16x32_bf16(af0[ks], b0, ar0, 0, 0, 0);
                ar1 = __builtin_amdgcn_mfma_f32_16x16x32_bf16(af1[ks], b0, ar1, 0, 0, 0);
                az0 = __builtin_amdgcn_mfma_f32_16x16x32_bf16(af0[ks], b1, az0, 0, 0, 0);
                az1 = __builtin_amdgcn_mfma_f32_16x16x32_bf16(af1[ks], b1, az1, 0, 0, 0);
                if (ks < 2) {
                    axn0 = __builtin_amdgcn_mfma_f32_16x16x32_bf16(af0[ks], b2, axn0, 0, 0, 0);
                    axn1 = __builtin_amdgcn_mfma_f32_16x16x32_bf16(af1[ks], b2, axn1, 0, 0, 0);
                } else {
                    ahn0 = __builtin_amdgcn_mfma_f32_16x16x32_bf16(af0[ks], b2, ahn0, 0, 0, 0);
                    ahn1 = __builtin_amdgcn_mfma_f32_16x16x32_bf16(af1[ks], b2, ahn1, 0, 0, 0);
                }
            }
            #pragma unroll
            for (int rr = 0; rr < 4; rr++) {
                const int idx = tswz(kg * 4 + rr, w * 16 + row);
                {
                    const float r_ = sigm(ar0[rr] + br_[w]);
                    const float z_ = sigm(az0[rr] + bz_[w]);
                    const float n_ = tanh_f(axn0[rr] + bxn_[w] + r_ * (ahn0[rr] + bhn_[w]));
                    const float h_ = bf2f(bufA[idx]);
                    bufA[idx] = f2bf_hw((1.f - z_) * n_ + z_ * h_);
                }
                {
                    const float r_ = sigm(ar1[rr] + br_[w]);
                    const float z_ = sigm(az1[rr] + bz_[w]);
                    const float n_ = tanh_f(axn1[rr] + bxn_[w] + r_ * (ahn1[rr] + bhn_[w]));
                    const float h_ = bf2f(bufB[idx]);
                    bufB[idx] = f2bf_hw((1.f - z_) * n_ + z_ * h_);
                }
            }
        }
        // bulk store: four contiguous 1KB bursts
        const int r8 = lane >> 3, c8 = (lane & 7) * 8;
        bf8_t oA0 = *(const bf8_t*)&bufA[tswz(r8, c8)];
        bf8_t oA1 = *(const bf8_t*)&bufA[tswz(8 + r8, c8)];
        bf8_t oB0 = *(const bf8_t*)&bufB[tswz(r8, c8)];
        bf8_t oB1 = *(const bf8_t*)&bufB[tswz(8 + r8, c8)];
        *(bf8_t*)(msg + (size_t)base * 64 + r8 * 64 + c8) = oA0;
        *(bf8_t*)(msg + (size_t)base * 64 + (8 + r8) * 64 + c8) = oA1;
        *(bf8_t*)(msg + (size_t)(base + 16) * 64 + r8 * 64 + c8) = oB0;
        *(bf8_t*)(msg + (size_t)(base + 16) * 64 + (8 + r8) * 64 + c8) = oB1;
    }
}

__launch_bounds__(256, 1)
__global__ void k_lstm(const int* __restrict__ dst_s, const u16* __restrict__ nfeat_new,
                       const u16* __restrict__ wpack, const float* __restrict__ bb,
                       const float* __restrict__ g_ln, const float* __restrict__ b_ln,
                       u16* __restrict__ efeat, u16* __restrict__ equery) {
    __shared__ u16 sW[32768];
    __shared__ u16 sBuf[4][1024];
    const int tid = threadIdx.x;
    const int lane = tid & 63;
    const int wv = tid >> 6;
    {
        const uint4* gsrc = (const uint4*)wpack;
        uint4* ldst = (uint4*)sW;
        #pragma unroll
        for (int i = 0; i < 16; i++) ldst[tid + i * 256] = gsrc[tid + i * 256];
    }
    __syncthreads();

    const int row = lane & 15, kg = lane >> 4;
    u16* buf = &sBuf[wv][0];
    float lgv[4], lbv[4];
    #pragma unroll
    for (int w = 0; w < 4; w++) { lgv[w] = g_ln[w * 16 + row]; lbv[w] = b_ln[w * 16 + row]; }

    const int NCH = EN / 16;
    const int stride = gridDim.x * 4;
    int ch = blockIdx.x * 4 + wv;
    bf8_t pn0 = {}, pn1 = {}, pe0 = {}, pe1 = {};
    if (ch < NCH) {
        const int de = dst_s[ch * 16 + row];
        pn0 = *(const bf8_t*)(nfeat_new + (size_t)de * 64 + kg * 8);
        pn1 = *(const bf8_t*)(nfeat_new + (size_t)de * 64 + 32 + kg * 8);
        pe0 = *(const bf8_t*)(efeat + (size_t)(ch * 16 + row) * 64 + kg * 8);
        pe1 = *(const bf8_t*)(efeat + (size_t)(ch * 16 + row) * 64 + 32 + kg * 8);
    }

    for (; ch < NCH; ch += stride) {
        const int base = ch * 16;
        const int e = base + row;
        bf8_t af[4];
        af[0] = pn0;
        af[1] = pn1;
        af[2] = pe0;
        af[3] = pe1;
        // stage equery-old into the wave tile (swizzled)
        {
            bf8_t q0 = *(const bf8_t*)(equery + (size_t)e * 64 + kg * 8);
            bf8_t q1 = *(const bf8_t*)(equery + (size_t)e * 64 + 32 + kg * 8);
            *(bf8_t*)&buf[tswz(row, kg * 8)] = q0;
            *(bf8_t*)&buf[tswz(row, kg * 8 + 32)] = q1;
        }
        // prefetch next chunk's nfeat_new gather (hidden under the gate loop)
        {
            const int nch = ch + stride;
            if (nch < NCH) {
                const int de = dst_s[nch * 16 + row];
                pn0 = *(const bf8_t*)(nfeat_new + (size_t)de * 64 + kg * 8);
                pn1 = *(const bf8_t*)(nfeat_new + (size_t)de * 64 + 32 + kg * 8);
            }
        }

        // hc[w][rr] = packed (bf16 hh, bf16 cc); LN sums stay exact f32
        unsigned hc[4][4];
        float sh[4] = {0, 0, 0, 0}, sh2[4] = {0, 0, 0, 0};
        float sc[4] = {0, 0, 0, 0}, sc2[4] = {0, 0, 0, 0};

        #pragma unroll
        for (int w = 0; w < 4; w++) {
            facc_t ai = {0.f, 0.f, 0.f, 0.f}, afv = ai, ag = ai, ao = ai;
            #pragma unroll
            for (int ks = 0; ks < 4; ks++) {
                const int rb = (ks * 16 + w * 4) * 512 + lane * 8;
                bf8_t b0 = *(const bf8_t*)&sW[rb];
                bf8_t b1 = *(const bf8_t*)&sW[rb + 512];
                bf8_t b2 = *(const bf8_t*)&sW[rb + 1024];
                bf8_t b3 = *(const bf8_t*)&sW[rb + 1536];
                ai  = __builtin_amdgcn_mfma_f32_16x16x32_bf16(af[ks], b0, ai, 0, 0, 0);
                afv = __builtin_amdgcn_mfma_f32_16x16x32_bf16(af[ks], b1, afv, 0, 0, 0);
                ag  = __builtin_amdgcn_mfma_f32_16x16x32_bf16(af[ks], b2, ag, 0, 0, 0);
                ao  = __builtin_amdgcn_mfma_f32_16x16x32_bf16(af[ks], b3, ao, 0, 0, 0);
            }
            const int d = w * 16 + row;
            const float bi = bb[d], bf_ = bb[64 + d], bg = bb[128 + d], bo = bb[192 + d];
            #pragma unroll
            for (int rr = 0; rr < 4; rr++) {
                const int idx = tswz(kg * 4 + rr, d);
                const float eq = bf2f(buf[idx]);
                const float ci = sigm(ai[rr] + bi);
                const float cf = sigm(afv[rr] + bf_);
                const float cg = tanh_f(ag[rr] + bg);
                const float co = sigm(ao[rr] + bo);
                const float c_ = cf * eq + ci * cg;
                const float h_ = co * tanh_f(c_);
                hc[w][rr] = cvtpk(h_, c_);
                sh[rr] += h_; sh2[rr] += h_ * h_;
                sc[rr] += c_; sc2[rr] += c_ * c_;
            }
        }
        #pragma unroll
        for (int off = 1; off < 16; off <<= 1) {
            #pragma unroll
            for (int rr = 0; rr < 4; rr++) {
                sh[rr] += __shfl_xor(sh[rr], off, 64);
                sh2[rr] += __shfl_xor(sh2[rr], off, 64);
                sc[rr] += __shfl_xor(sc[rr], off, 64);
                sc2[rr] += __shfl_xor(sc2[rr], off, 64);
            }
        }
        float hm[4], hrs[4], cm[4], crs[4];
        #pragma unroll
        for (int rr = 0; rr < 4; rr++) {
            hm[rr] = sh[rr] * (1.f / 64.f);
            hrs[rr] = rsqrtf(sh2[rr] * (1.f / 64.f) - hm[rr] * hm[rr] + EPS_);
            cm[rr] = sc[rr] * (1.f / 64.f);
            crs[rr] = rsqrtf(sc2[rr] * (1.f / 64.f) - cm[rr] * cm[rr] + EPS_);
        }
        // prefetch next chunk's efeat rows (hidden under the two output passes)
        {
            const int nch = ch + stride;
            if (nch < NCH) {
                const size_t ne = (size_t)(nch * 16 + row) * 64;
                pe0 = *(const bf8_t*)(efeat + ne + kg * 8);
                pe1 = *(const bf8_t*)(efeat + ne + 32 + kg * 8);
            }
        }
        // pass 1: equery-new in place (cc = hi half of hc), bulk store
        #pragma unroll
        for (int w = 0; w < 4; w++) {
            #pragma unroll
            for (int rr = 0; rr < 4; rr++) {
                const int idx = tswz(kg * 4 + rr, w * 16 + row);
                const float eqo = bf2f(buf[idx]);
                const float c_ = bf2f((u16)(hc[w][rr] >> 16));
                buf[idx] = f2bf_hw(eqo + (c_ - cm[rr]) * crs[rr] * lgv[w] + lbv[w]);
            }
        }
        {
            const int r8 = lane >> 3, c8 = (lane & 7) * 8;
            bf8_t o0 = *(const bf8_t*)&buf[tswz(r8, c8)];
            bf8_t o1 = *(const bf8_t*)&buf[tswz(8 + r8, c8)];
            *(bf8_t*)(equery + (size_t)base * 64 + r8 * 64 + c8) = o0;
            *(bf8_t*)(equery + (size_t)base * 64 + (8 + r8) * 64 + c8) = o1;
        }
        // restage efeat-old (still in af[2..3])
        *(bf8_t*)&buf[tswz(row, kg * 8)] = af[2];
        *(bf8_t*)&buf[tswz(row, kg * 8 + 32)] = af[3];
        // pass 2: efeat-new in place (hh = lo half of hc), bulk store
        #pragma unroll
        for (int w = 0; w < 4; w++) {
            #pragma unroll
            for (int rr = 0; rr < 4; rr++) {
                const int idx = tswz(kg * 4 + rr, w * 16 + row);
                const float efo = bf2f(buf[idx]);
                const float h_ = bf2f((u16)(hc[w][rr] & 0xFFFFu));
                buf[idx] = f2bf_hw(efo + (h_ - hm[rr]) * hrs[rr] * lgv[w] + lbv[w]);
            }
        }
        {
            const int r8 = lane >> 3, c8 = (lane & 7) * 8;
            bf8_t o0 = *(const bf8_t*)&buf[tswz(r8, c8)];
            bf8_t o1 = *(const bf8_t*)&buf[tswz(8 + r8, c8)];
            *(bf8_t*)(efeat + (size_t)base * 64 + r8 * 64 + c8) = o0;
            *(bf8_t*)(efeat + (size_t)base * 64 + (8 + r8) * 64 + c8) = o1;
        }
    }
}

// k_node: msg is CSR-ordered -> the aggregation loop reads CONTIGUOUS rows.
__launch_bounds__(256)
__global__ void k_node(const int* __restrict__ row_ptr,
                       const u16* __restrict__ msg, const float* __restrict__ avg_sum,
                       const u16* __restrict__ wpack, const float* __restrict__ pb,
                       const float* __restrict__ g_ln, const float* __restrict__ b_ln,
                       u16* __restrict__ nfeat, u16* __restrict__ nfeat_new) {
    __shared__ u16 sAgg[16 * 280];
    __shared__ float sS[16], sT[16];
    __shared__ float sRed[4][16][2];
    const int lane = threadIdx.x & 63;
    const int w = threadIdx.x >> 6;
    const int base = blockIdx.x * 16;
    const float avg = avg_sum[0] * (1.f / (float)NN);

    bf8_t bw[8][3];
    #pragma unroll
    for (int ks = 0; ks < 8; ks++) {
        #pragma unroll
        for (int y = 0; y < 3; y++)
            bw[ks][y] = ((const bf8_t*)wpack)[((ks * 3 + y) * 4 + w) * 64 + lane];
    }

    float samp[4], satt[4];
    #pragma unroll
    for (int q = 0; q < 4; q++) {
        const int m = w * 4 + q;
        const int v = base + m;
        const int rs = row_ptr[v], re = row_ptr[v + 1];
        float s = 0.f, s2 = 0.f, mx = -INFINITY, mn = INFINITY;
        for (int i = rs; i < re; i++) {
            const float mv = bf2f(msg[(size_t)i * 64 + lane]);
            s += mv; s2 += mv * mv; mx = fmaxf(mx, mv); mn = fminf(mn, mv);
        }
        const float deg = (float)(re - rs);
        const float dsafe = fmaxf(deg, 1.f);
        const float mean = s / dsafe;
        const float sq = s2 / dsafe;
        const bool has = (re - rs) > 0;
        const float amx = has ? mx : 0.f;
        const float amn = has ? mn : 0.f;
        const float astd = sqrtf(fmaxf(sq - mean * mean, 0.f) + EPS_);
        uint2 pk;
        pk.x = cvtpk(mean, amx);
        pk.y = cvtpk(amn, astd);
        *(uint2*)&sAgg[m * 280 + lane * 4] = pk;
        const float ld = logf(deg + 1.f);
        samp[q] = ld / avg;
        satt[q] = ld > 0.f ? avg / fmaxf(ld, EPS_) : 0.f;
    }
    if (lane == 0) {
        #pragma unroll
        for (int q = 0; q < 4; q++) { sS[w * 4 + q] = samp[q]; sT[w * 4 + q] = satt[q]; }
    }
    __syncthreads();

    facc_t c0 = {0.f, 0.f, 0.f, 0.f}, c1 = c0, c2 = c0;
    const int arow = lane & 15, acol = (lane >> 4) * 8;
    #pragma unroll
    for (int ks = 0; ks < 8; ks++) {
        bf8_t af = *(const bf8_t*)&sAgg[arow * 280 + ks * 32 + acol];
        c0 = __builtin_amdgcn_mfma_f32_16x16x32_bf16(af, bw[ks][0], c0, 0, 0, 0);
        c1 = __builtin_amdgcn_mfma_f32_16x16x32_bf16(af, bw[ks][1], c1, 0, 0, 0);
        c2 = __builtin_amdgcn_mfma_f32_16x16x32_bf16(af, bw[ks][2], c2, 0, 0, 0);
    }

    const int d = w * 16 + (lane & 15);
    const float pbl = pb[d], lg = g_ln[d], lb = b_ln[d];
    float nf[4];
    #pragma unroll
    for (int rr = 0; rr < 4; rr++) {
        const int m = (lane >> 4) * 4 + rr;
        nf[rr] = pbl + c0[rr] + sS[m] * c1[rr] + sT[m] * c2[rr];
        nfeat_new[(size_t)(base + m) * 64 + d] = f2bf_hw(nf[rr]);
    }
    float ps[4], ps2[4];
    #pragma unroll
    for (int rr = 0; rr < 4; rr++) { ps[rr] = nf[rr]; ps2[rr] = nf[rr] * nf[rr]; }
    #pragma unroll
    for (int off = 1; off < 16; off <<= 1) {
        #pragma unroll
        for (int rr = 0; rr < 4; rr++) {
            ps[rr] += __shfl_xor(ps[rr], off, 64);
            ps2[rr] += __shfl_xor(ps2[rr], off, 64);
        }
    }
    if ((lane & 15) == 0) {
        #pragma unroll
        for (int rr = 0; rr < 4; rr++) {
            const int m = (lane >> 4) * 4 + rr;
            sRed[w][m][0] = ps[rr];
            sRed[w][m][1] = ps2[rr];
        }
    }
    __syncthreads();
    #pragma unroll
    for (int rr = 0; rr < 4; rr++) {
        const int m = (lane >> 4) * 4 + rr;
        float ts = 0.f, ts2 = 0.f;
        #pragma unroll
        for (int w2 = 0; w2 < 4; w2++) { ts += sRed[w2][m][0]; ts2 += sRed[w2][m][1]; }
        const float mean = ts * (1.f / 64.f);
        const float var = ts2 * (1.f / 64.f) - mean * mean;
        const size_t off = (size_t)(base + m) * 64 + d;
        nfeat[off] = f2bf_hw(bf2f(nfeat[off]) + (nf[rr] - mean) * rsqrtf(var + EPS_) * lg + lb);
    }
}

__global__ void k_snap(const int* __restrict__ tgt, const int* __restrict__ src,
                       const int* __restrict__ inv,
                       const u16* __restrict__ efeat, const u16* __restrict__ equery,
                       const u16* __restrict__ nfeat,
                       float* jk_e, float* jk_q, float* jk_n) {
    int t = blockIdx.x, d = threadIdx.x;
    int e = tgt[t];
    int pos = inv[e];
    jk_e[t * 64 + d] = bf2f(efeat[(size_t)pos * 64 + d]);
    jk_q[t * 64 + d] = bf2f(equery[(size_t)pos * 64 + d]);
    int v = src[e];
    jk_n[t * 64 + d] = bf2f(nfeat[v * 64 + d]);
}

// ---------------- output head ----------------

__global__ void k_jk(const float* __restrict__ jk_e, const float* __restrict__ jk_q, const float* __restrict__ jk_n,
                     const float* __restrict__ ejk_w, const float* __restrict__ ejk_b,
                     const float* __restrict__ qjk_w, const float* __restrict__ qjk_b,
                     const float* __restrict__ njk_w, const float* __restrict__ njk_b,
                     float* ejk_o, float* qjk_o, float* njk_o) {
    int t = blockIdx.x, d = threadIdx.x;
    float ae = ejk_b[d], aq = qjk_b[d], an_ = njk_b[d];
    for (int l = 0; l < 3; l++) {
        for (int dd = 0; dd < 64; dd++) {
            int k = l * 64 + dd;
            ae += jk_e[(l * 64 + t) * 64 + dd] * ejk_w[k * 64 + d];
            aq += jk_q[(l * 64 + t) * 64 + dd] * qjk_w[k * 64 + d];
            an_ += jk_n[(l * 64 + t) * 64 + dd] * njk_w[k * 64 + d];
        }
    }
    ejk_o[t * 64 + d] = ae;
    qjk_o[t * 64 + d] = aq;
    njk_o[t * 64 + d] = an_;
}

__global__ void k_final(const float* __restrict__ ejk_o, const float* __restrict__ qjk_o,
                        const float* __restrict__ njk_o,
                        const float* __restrict__ fc_w, const float* __restrict__ fc_b,
                        float* out) {
    int b = blockIdx.x, d = threadIdx.x;
    int t0 = 2 * b, t1 = 2 * b + 1;
    float r = ejk_o[t0 * 64 + d] * fc_w[d] + qjk_o[t0 * 64 + d] * fc_w[64 + d]
            + njk_o[t0 * 64 + d] * fc_w[128 + d] + njk_o[t1 * 64 + d] * fc_w[192 + d];
    float lf = ejk_o[t1 * 64 + d] * fc_w[d] + qjk_o[t1 * 64 + d] * fc_w[64 + d]
             + njk_o[t1 * 64 + d] * fc_w[128 + d] + njk_o[t0 * 64 + d] * fc_w[192 + d];
    #pragma unroll
    for (int off = 32; off > 0; off >>= 1) { r += __shfl_xor(r, off, 64); lf += __shfl_xor(lf, off, 64); }
    if (d == 0) out[b] = fmaxf(r + fc_b[0], lf + fc_b[0]);
}

// ---------------- host launcher ----------------

extern "C" void kernel_launch(void* const* d_in, const int* in_sizes, int n_in,
                              void* d_out, int out_size, void* d_ws, size_t ws_size,
                              hipStream_t stream) {
    const int* src   = (const int*)d_in[0];
    const int* dst   = (const int*)d_in[1];
    const int* etype = (const int*)d_in[2];
    const int* egid  = (const int*)d_in[3];
    const int* tgt   = (const int*)d_in[4];
    const float* query_emb = (const float*)d_in[6];
    const float* eqp_w = (const float*)d_in[7];
    const float* eqp_b = (const float*)d_in[8];
    const float* rel_w = (const float*)d_in[9];
    const float* gru_wx = (const float*)d_in[10];
    const float* gru_wh = (const float*)d_in[11];
    const float* gru_bx = (const float*)d_in[12];
    const float* gru_bh = (const float*)d_in[13];
    const float* pna_w = (const float*)d_in[14];
    const float* pna_b = (const float*)d_in[15];
    const float* lstm_wx = (const float*)d_in[16];
    const float* lstm_wh = (const float*)d_in[17];
    const float* lstm_b = (const float*)d_in[18];
    const float* ln_g = (const float*)d_in[19];
    const float* ln_b = (const float*)d_in[20];
    const float* ejk_w = (const float*)d_in[21];
    const float* ejk_b = (const float*)d_in[22];
    const float* njk_w = (const float*)d_in[23];
    const float* njk_b = (const float*)d_in[24];
    const float* qjk_w = (const float*)d_in[25];
    const float* qjk_b = (const float*)d_in[26];
    const float* fc_w = (const float*)d_in[27];
    const float* fc_b = (const float*)d_in[28];

    u16* q16 = (u16*)d_ws;
    u16* equery = q16;     q16 += (size_t)EN * 64;
    u16* efeat = q16;      q16 += (size_t)EN * 64;
    u16* msg = q16;        q16 += (size_t)EN * 64;
    u16* nfeat = q16;      q16 += (size_t)NN * 64;
    u16* nfeat_new = q16;  q16 += (size_t)NN * 64;
    u16* wpg = q16;        q16 += 3 * 24576;
    u16* wpl = q16;        q16 += 3 * 32768;
    u16* wpp = q16;        q16 += 3 * 49152;
    u16* msg_row = q16;    q16 += 32 * 64;
    q16 += 32;  // alignment pad
    float* p = (float*)q16;
    float* tgt_q = p;     p += 64 * 64;
    float* eq_g = p;      p += 32 * 64;
    float* jk_e = p;      p += 3 * 64 * 64;
    float* jk_q = p;      p += 3 * 64 * 64;
    float* jk_n = p;      p += 3 * 64 * 64;
    float* ejk_o = p;     p += 64 * 64;
    float* qjk_o = p;     p += 64 * 64;
    float* njk_o = p;     p += 64 * 64;
    float* avg_sum = p;   p += 64;
    int* ip = (int*)p;
    int* row_ptr = ip; ip += NN + 1;
    int* fillp = ip;   ip += NN;
    int* cnt = ip;     ip += NN;
    int* outcnt = ip;  ip += NN;
    int* inv = ip;     ip += EN;
    int* src_s = ip;   ip += EN;
    int* dst_s = ip;   ip += EN;
    int* ty_s = ip;    ip += EN;
    int* gid_s = ip;   ip += EN;
    int* bsum = ip;    ip += 64;
    int* boff = ip;    ip += 64;
    if ((size_t)((char*)ip - (char*)d_ws) > ws_size) return;

    k_init<<<4096, 256, 0, stream>>>(efeat, nfeat, cnt, outcnt, avg_sum);
    k_count<<<1024, 256, 0, stream>>>(src, dst, cnt, outcnt);
    k_scan1<<<40, 1024, 0, stream>>>(cnt, row_ptr, bsum);
    k_scan2<<<1, 64, 0, stream>>>(bsum, boff, row_ptr);
    k_scan3<<<40, 1024, 0, stream>>>(row_ptr, fillp, boff);
    k_fill<<<1024, 256, 0, stream>>>(src, dst, etype, egid, fillp, inv,
                                     src_s, dst_s, ty_s, gid_s);
    k_avg<<<(NN + 255) / 256, 256, 0, stream>>>(outcnt, avg_sum);
    k_prep_small<<<32, 64, 0, stream>>>(tgt, etype, inv, query_emb, eqp_w, eqp_b,
                                        gru_wx, gru_bx, gru_bh, tgt_q, efeat, eq_g, msg_row);
    k_bcast<<<4096, 256, 0, stream>>>(gid_s, eq_g, msg_row, equery, msg);
    k_pack_all<<<dim3(56, 3), 256, 0, stream>>>(gru_wx, gru_wh, lstm_wx, lstm_wh, pna_w,
                                                wpg, wpl, wpp);

    for (int l = 0; l < 3; l++) {
        if (l == 0) {
            // msg already broadcast by k_bcast; only the 64 target edges differ
            k_gru0_fix<<<64, 64, 0, stream>>>(tgt, etype, inv, equery, efeat, rel_w,
                gru_wx, gru_wh, gru_bx, gru_bh, msg);
        } else {
            k_gru<<<512, 256, 0, stream>>>(src_s, ty_s, nfeat, equery, efeat,
                rel_w + (size_t)l * NR * 64, wpg + (size_t)l * 24576,
                gru_bx + (size_t)l * 192, gru_bh + (size_t)l * 192, msg);
        }
        k_node<<<NN / 16, 256, 0, stream>>>(row_ptr, msg, avg_sum,
            wpp + (size_t)l * 49152, pna_b + (size_t)l * 64,
            ln_g + (size_t)l * 64, ln_b + (size_t)l * 64, nfeat, nfeat_new);
        k_lstm<<<512, 256, 0, stream>>>(dst_s, nfeat_new, wpl + (size_t)l * 32768,
            lstm_b + (size_t)l * 256,
            ln_g + (size_t)l * 64, ln_b + (size_t)l * 64, efeat, equery);
        k_snap<<<64, 64, 0, stream>>>(tgt, src, inv, efeat, equery, nfeat,
            jk_e + l * 4096, jk_q + l * 4096, jk_n + l * 4096);
    }

    k_jk<<<64, 64, 0, stream>>>(jk_e, jk_q, jk_n, ejk_w, ejk_b, qjk_w, qjk_b, njk_w, njk_b,
                                ejk_o, qjk_o, njk_o);
    k_final<<<32, 64, 0, stream>>>(ejk_o, qjk_o, njk_o, fc_w, fc_b, (float*)d_out);
}